// Round 8
// baseline (488.886 us; speedup 1.0000x reference)
//
#include <hip/hip_runtime.h>
#include <hip/hip_bf16.h>

typedef __hip_bfloat16 bf16;

#define R_NUM 40000
#define E_NUM 500000

// wbuf layout (f32 element offsets)
#define W_P1W 0
#define W_P1B 4096
#define W_APW 4160    // 2*128*64
#define W_APB 20544   // 2*64
#define W_ABIN 20672  // 2*10*8
#define W_AVEC 20832  // 2*8*8
#define W_AW 20960    // 2*64*64
#define W_AB 29152
#define W_RW 29280
#define W_RB 37472
#define W_END 37600

// ws byte offsets
#define O_FLAG 0
#define O_WBUF 256
#define O_ROWP 150784
#define O_CNTS 310784
#define O_TMP 470784
#define O_PART 634624
#define O_STB 635136
#define O_BIG 2635136
#define XM_BYTES 20480000ull
#define NEED_FULL (O_BIG + 3 * XM_BYTES)  // 64,075,136: XMa + XMb + HR
#define NEED_XM2 (O_BIG + 2 * XM_BYTES)   // 43,595,136 (proven to fit)
#define NEED_XM1 (O_BIG + 1 * XM_BYTES)   // 23,115,136

static __device__ __forceinline__ float b2f(bf16 x) { return __bfloat162float(x); }
static __device__ __forceinline__ float ldv(const float* p, size_t i) { return p[i]; }
static __device__ __forceinline__ float ldv(const bf16* p, size_t i) { return __bfloat162float(p[i]); }
static __device__ __forceinline__ void stv(float* p, size_t i, float v) { p[i] = v; }
static __device__ __forceinline__ void stv(bf16* p, size_t i, float v) { p[i] = __float2bfloat16(v); }

// ---------------- runtime dtype detection ----------------

__global__ void k_detect(const unsigned int* __restrict__ trip_w,
                         const unsigned short* __restrict__ emb_w, int* __restrict__ flag) {
  int lane = threadIdx.x;
  unsigned int acc = 0;
  for (int i = lane; i < 1024; i += 64) acc |= trip_w[2 * i + 1];
  int votes = 0;
  for (int i = lane; i < 2048; i += 64) {
    unsigned short u = emb_w[2 * i];
    int ex = (u >> 7) & 0xFF;
    if (ex >= 90 && ex <= 130) votes++;
  }
  for (int off = 1; off < 64; off <<= 1) {
    acc |= __shfl_xor(acc, off);
    votes += __shfl_xor(votes, off);
  }
  if (lane == 0) {
    flag[0] = (acc == 0) ? 1 : 0;
    flag[1] = (votes < 1024) ? 1 : 0;
  }
}

// ---------------- weights -> f32 scratch ----------------

__global__ void k_wconv(const void* p1w, const void* p1b, const void* apw, const void* apb,
                        const void* abin, const void* avec, const void* aw, const void* ab,
                        const void* rw, const void* rb, const int* __restrict__ flag,
                        float* __restrict__ wbuf) {
  int i = blockIdx.x * 256 + threadIdx.x;
  if (i >= W_END) return;
  const void* src;
  int off;
  if (i < W_P1B) { src = p1w; off = i - W_P1W; }
  else if (i < W_APW) { src = p1b; off = i - W_P1B; }
  else if (i < W_APB) { src = apw; off = i - W_APW; }
  else if (i < W_ABIN) { src = apb; off = i - W_APB; }
  else if (i < W_AVEC) { src = abin; off = i - W_ABIN; }
  else if (i < W_AW) { src = avec; off = i - W_AVEC; }
  else if (i < W_AB) { src = aw; off = i - W_AW; }
  else if (i < W_RW) { src = ab; off = i - W_AB; }
  else if (i < W_RB) { src = rw; off = i - W_RW; }
  else { src = rb; off = i - W_RB; }
  wbuf[i] = flag[1] ? ((const float*)src)[off] : b2f(((const bf16*)src)[off]);
}

// ---------------- edge decode ----------------

static __device__ __forceinline__ void load_edge(const unsigned int* __restrict__ w, int e,
                                                 int i64, int& h, int& t, int& b) {
  if (i64) {
    h = (int)w[6 * e + 0];
    t = (int)w[6 * e + 2];
    b = (int)w[6 * e + 4];
  } else {
    h = (int)w[3 * e + 0];
    t = (int)w[3 * e + 1];
    b = (int)w[3 * e + 2];
  }
}

// ---------------- counting sort by head ----------------

__global__ void k_hist(const unsigned int* __restrict__ trip_w, const int* __restrict__ flag,
                       int* __restrict__ counts) {
  int e = blockIdx.x * 256 + threadIdx.x;
  if (e >= E_NUM) return;
  int h, t, b;
  load_edge(trip_w, e, flag[0], h, t, b);
  atomicAdd(&counts[h], 1);
}

__global__ void k_scan_a(const int* __restrict__ counts, int* __restrict__ tmp,
                         int* __restrict__ partial) {
  __shared__ int sd[1024];
  int tid = threadIdx.x;
  int idx = blockIdx.x * 1024 + tid;
  int v = (idx < R_NUM) ? counts[idx] : 0;
  sd[tid] = v;
  __syncthreads();
  for (int off = 1; off < 1024; off <<= 1) {
    int t = (tid >= off) ? sd[tid - off] : 0;
    __syncthreads();
    sd[tid] += t;
    __syncthreads();
  }
  if (idx < R_NUM) tmp[idx] = sd[tid];
  if (tid == 1023) partial[blockIdx.x] = sd[1023];
}

// fused: per-block offset = sum(partial[0..bid-1]) computed by wave 0, then add
__global__ void k_scan_c(const int* __restrict__ counts, const int* __restrict__ tmp,
                         const int* __restrict__ partial, int* __restrict__ row_ptr) {
  __shared__ int soff;
  if (threadIdx.x < 64) {
    int lane = threadIdx.x;
    int p = (lane < (int)blockIdx.x) ? partial[lane] : 0;  // gridDim 40 <= 64
    for (int d = 1; d < 64; d <<= 1) p += __shfl_xor(p, d);
    if (lane == 0) soff = p;
  }
  __syncthreads();
  int idx = blockIdx.x * 1024 + threadIdx.x;
  if (idx < R_NUM) row_ptr[idx] = tmp[idx] - counts[idx] + soff;
}

// scatter bumps row_ptr: afterwards row_ptr[r] == end(r); beg(r) = r ? row_ptr[r-1] : 0
__global__ void k_scatter(const unsigned int* __restrict__ trip_w, const int* __restrict__ flag,
                          int* __restrict__ row_ptr, int* __restrict__ stb) {
  int e = blockIdx.x * 256 + threadIdx.x;
  if (e >= E_NUM) return;
  int h, t, b;
  load_edge(trip_w, e, flag[0], h, t, b);
  int pos = atomicAdd(&row_ptr[h], 1);
  stb[pos] = (t & 0xFFFF) | (b << 16);
}

// ---------------- fused emb0 (+XM l0) (+HR l0) ----------------
// mode 0: emb only; 1: +XM; 2: +XM +HR

__global__ void k_emb0xm(const void* __restrict__ A, const int* __restrict__ flag,
                         const float* __restrict__ wbuf, float* __restrict__ emb,
                         float2* __restrict__ XM, float2* __restrict__ HR, int mode) {
  int j = threadIdx.x & 63;
  int g = threadIdx.x >> 6;
  int r0 = blockIdx.x * 16 + g * 4;
  int f32 = flag[1];
  __shared__ float sA[16][64];
  for (int k = threadIdx.x; k < 1024; k += 256) {
    int rr = k >> 6, cc = k & 63;
    size_t idx = (size_t)(blockIdx.x * 16 + rr) * 64 + cc;
    sA[rr][cc] = f32 ? ((const float*)A)[idx] : b2f(((const bf16*)A)[idx]);
  }
  __syncthreads();
  const float* W = wbuf + W_P1W;
  float a[4] = {0.f, 0.f, 0.f, 0.f};
  int base = g * 4;
  for (int i = 0; i < 64; i++) {
    float w = W[i * 64 + j];
#pragma unroll
    for (int n = 0; n < 4; n++) a[n] = fmaf(sA[base + n][i], w, a[n]);
  }
  float bj = wbuf[W_P1B + j];
#pragma unroll
  for (int n = 0; n < 4; n++) {
    a[n] = fmaxf(a[n] + bj, 0.f);
    emb[(size_t)(r0 + n) * 64 + j] = a[n];
  }
  if (mode == 0) return;
  __syncthreads();
#pragma unroll
  for (int n = 0; n < 4; n++) sA[base + n][j] = a[n];
  __syncthreads();
  {
    const float* pwb = wbuf + W_APW + 4096;  // layer-0 bottom proj
    const float* aw = wbuf + W_AW;
    float axt[4] = {0.f, 0.f, 0.f, 0.f};
    float amt[4] = {0.f, 0.f, 0.f, 0.f};
    for (int i = 0; i < 64; i++) {
      float wt = pwb[i * 64 + j];
      float wm = aw[i * 64 + j];
#pragma unroll
      for (int n = 0; n < 4; n++) {
        float e = sA[base + n][i];
        axt[n] = fmaf(e, wt, axt[n]);
        amt[n] = fmaf(e, wm, amt[n]);
      }
    }
    float abj = wbuf[W_AB + j];
#pragma unroll
    for (int n = 0; n < 4; n++)
      XM[(size_t)(r0 + n) * 64 + j] = make_float2(axt[n], amt[n] + abj);
  }
  if (mode < 2) return;
  {
    const float* pwt = wbuf + W_APW;  // layer-0 top proj
    const float* rw = wbuf + W_RW;
    float axh[4] = {0.f, 0.f, 0.f, 0.f};
    float ars[4] = {0.f, 0.f, 0.f, 0.f};
    for (int i = 0; i < 64; i++) {
      float wh = pwt[i * 64 + j];
      float wr = rw[i * 64 + j];
#pragma unroll
      for (int n = 0; n < 4; n++) {
        float e = sA[base + n][i];
        axh[n] = fmaf(e, wh, axh[n]);
        ars[n] = fmaf(e, wr, ars[n]);
      }
    }
    float pbj = wbuf[W_APB + j];
    float rbj = wbuf[W_RB + j];
#pragma unroll
    for (int n = 0; n < 4; n++)
      HR[(size_t)(r0 + n) * 64 + j] = make_float2(axh[n] + pbj, fmaxf(ars[n] + rbj, 0.f));
  }
}

// ---------------- standalone XM (XM1 fallback path) ----------------

__global__ void k_xm(const float* __restrict__ emb, const float* __restrict__ wbuf, int l,
                     float2* __restrict__ XM) {
  int j = threadIdx.x & 63;
  int g = threadIdx.x >> 6;
  int r0 = blockIdx.x * 16 + g * 4;
  __shared__ float sE[16][64];
  for (int k = threadIdx.x; k < 1024; k += 256) {
    int rr = k >> 6, cc = k & 63;
    sE[rr][cc] = emb[(size_t)(blockIdx.x * 16 + rr) * 64 + cc];
  }
  __syncthreads();
  const float* pwb = wbuf + W_APW + l * 8192 + 4096;
  const float* aw = wbuf + W_AW + l * 4096;
  float axt[4] = {0.f, 0.f, 0.f, 0.f};
  float amt[4] = {0.f, 0.f, 0.f, 0.f};
  int base = g * 4;
  for (int i = 0; i < 64; i++) {
    float wt = pwb[i * 64 + j];
    float wm = aw[i * 64 + j];
#pragma unroll
    for (int n = 0; n < 4; n++) {
      float e = sE[base + n][i];
      axt[n] = fmaf(e, wt, axt[n]);
      amt[n] = fmaf(e, wm, amt[n]);
    }
  }
  float abj = wbuf[W_AB + l * 64 + j];
#pragma unroll
  for (int n = 0; n < 4; n++)
    XM[(size_t)(r0 + n) * 64 + j] = make_float2(axt[n], amt[n] + abj);
}

// ---------------- FULL edge kernel: HR-precomputed, window-16 prefetch ----------------
// __launch_bounds__(256,4): VGPR cap 128 so the 16-deep gather window stays in flight.

template <bool WXM>
__global__ void __launch_bounds__(256, 4) k_edge_full(
    const int* __restrict__ row_ptr, const int* __restrict__ stb, const float2* __restrict__ XM,
    float2* __restrict__ HR, const float* __restrict__ wbuf, int l, float* __restrict__ emb,
    float2* __restrict__ XMout) {
  __shared__ float sab[80];
  int tid = threadIdx.x;
  int lane = tid & 63;
  int w = tid >> 6;
  int hh = lane >> 3;
  if (tid < 80) {
    float a = wbuf[W_ABIN + l * 80 + tid];
    sab[tid] = (a > 0.f) ? a : 0.2f * a;
  }
  __syncthreads();
  float av = wbuf[W_AVEC + l * 64 + lane];
  const float* pwb1 = wbuf + W_APW + 8192 + 4096;  // layer-1 weights for epilogue
  const float* aw1 = wbuf + W_AW + 4096;
  const float* pwt1 = wbuf + W_APW + 8192;
  const float* rw1 = wbuf + W_RW + 4096;
  float ab1 = 0.f, pb1 = 0.f, rb1 = 0.f;
  if (WXM) {
    ab1 = wbuf[W_AB + 64 + lane];
    pb1 = wbuf[W_APB + 64 + lane];
    rb1 = wbuf[W_RB + 64 + lane];
  }

  int r0 = blockIdx.x * 16 + w * 4;
  for (int rr = 0; rr < 4; rr++) {
    int r = r0 + rr;
    float2 hr = HR[(size_t)r * 64 + lane];  // x = xh (bias folded), y = relu'd res
    float xh = hr.x;
    int beg = (r == 0) ? 0 : row_ptr[r - 1];
    int end = row_ptr[r];
    float num = 0.f, den = 0.f;
    for (int c = beg; c < end; c += 64) {
      int nc = min(64, end - c);
      int pl = (c + lane < end) ? stb[c + lane] : 0;
      for (int wb = 0; wb < nc; wb += 16) {
        int wn = min(16, nc - wb);
        int pk[16];
        float2 xmv[16];
#pragma unroll
        for (int k = 0; k < 16; k++) {
          if (k < wn) {
            pk[k] = __shfl(pl, wb + k);
            xmv[k] = XM[(size_t)(pk[k] & 0xFFFF) * 64 + lane];
          }
        }
#pragma unroll
        for (int k = 0; k < 16; k++) {
          if (k < wn) {
            float z = xh + xmv[k].x;
            z = (z > 0.f) ? z : 0.2f * z;
            float v = z * av;
            v += __shfl_xor(v, 1);
            v += __shfl_xor(v, 2);
            v += __shfl_xor(v, 4);
            float e = __expf(v + sab[(pk[k] >> 16) * 8 + hh]);
            den += e;
            num = fmaf(xmv[k].y, e, num);
          }
        }
      }
    }
    float o = fmaxf(num / (den + 1e-16f), 0.f) + hr.y;
    emb[(size_t)r * 64 + lane] = o;
    if (WXM) {  // produce layer-1 XM and HR rows (row-local, race-free)
      float xt = 0.f, mt = ab1, x2 = pb1, r2 = rb1;
#pragma unroll 16
      for (int i = 0; i < 64; i++) {
        float e = __shfl(o, i);
        xt = fmaf(e, pwb1[i * 64 + lane], xt);
        mt = fmaf(e, aw1[i * 64 + lane], mt);
        x2 = fmaf(e, pwt1[i * 64 + lane], x2);
        r2 = fmaf(e, rw1[i * 64 + lane], r2);
      }
      XMout[(size_t)r * 64 + lane] = make_float2(xt, mt);
      HR[(size_t)r * 64 + lane] = make_float2(x2, fmaxf(r2, 0.f));
    }
  }
}

// ---------------- XM2/XM1 edge kernel: in-kernel preamble, window-16 ----------------

template <bool WXM>
__global__ void __launch_bounds__(256, 4) k_edge_f(
    const int* __restrict__ row_ptr, const int* __restrict__ stb, const float2* __restrict__ XM,
    const float* __restrict__ wbuf, int l, float* __restrict__ emb, float2* __restrict__ XMout) {
  __shared__ float sab[80];
  int tid = threadIdx.x;
  int lane = tid & 63;
  int w = tid >> 6;
  int hh = lane >> 3;
  if (tid < 80) {
    float a = wbuf[W_ABIN + l * 80 + tid];
    sab[tid] = (a > 0.f) ? a : 0.2f * a;
  }
  __syncthreads();

  const float* pwt = wbuf + W_APW + l * 8192;
  const float* rwp = wbuf + W_RW + l * 4096;
  const float* pwb1 = wbuf + W_APW + 8192 + 4096;
  const float* aw1 = wbuf + W_AW + 4096;
  float av = wbuf[W_AVEC + l * 64 + lane];
  float xh0 = wbuf[W_APB + l * 64 + lane];
  float res0 = wbuf[W_RB + l * 64 + lane];
  float ab1 = WXM ? wbuf[W_AB + 64 + lane] : 0.f;

  int r0 = blockIdx.x * 16 + w * 4;
  for (int rr = 0; rr < 4; rr++) {
    int r = r0 + rr;
    float ev = emb[(size_t)r * 64 + lane];
    float xh = xh0, res = res0;
#pragma unroll 16
    for (int i = 0; i < 64; i++) {
      float e = __shfl(ev, i);
      xh = fmaf(e, pwt[i * 64 + lane], xh);
      res = fmaf(e, rwp[i * 64 + lane], res);
    }
    res = fmaxf(res, 0.f);

    int beg = (r == 0) ? 0 : row_ptr[r - 1];
    int end = row_ptr[r];
    float num = 0.f, den = 0.f;
    for (int c = beg; c < end; c += 64) {
      int nc = min(64, end - c);
      int pl = (c + lane < end) ? stb[c + lane] : 0;
      for (int wb = 0; wb < nc; wb += 16) {
        int wn = min(16, nc - wb);
        int pk[16];
        float2 xmv[16];
#pragma unroll
        for (int k = 0; k < 16; k++) {
          if (k < wn) {
            pk[k] = __shfl(pl, wb + k);
            xmv[k] = XM[(size_t)(pk[k] & 0xFFFF) * 64 + lane];
          }
        }
#pragma unroll
        for (int k = 0; k < 16; k++) {
          if (k < wn) {
            float z = xh + xmv[k].x;
            z = (z > 0.f) ? z : 0.2f * z;
            float v = z * av;
            v += __shfl_xor(v, 1);
            v += __shfl_xor(v, 2);
            v += __shfl_xor(v, 4);
            float e = __expf(v + sab[(pk[k] >> 16) * 8 + hh]);
            den += e;
            num = fmaf(xmv[k].y, e, num);
          }
        }
      }
    }

    float o = fmaxf(num / (den + 1e-16f), 0.f) + res;
    emb[(size_t)r * 64 + lane] = o;
    if (WXM) {
      float xt = 0.f, mt = ab1;
#pragma unroll 16
      for (int i = 0; i < 64; i++) {
        float e = __shfl(o, i);
        xt = fmaf(e, pwb1[i * 64 + lane], xt);
        mt = fmaf(e, aw1[i * 64 + lane], mt);
      }
      XMout[(size_t)r * 64 + lane] = make_float2(xt, mt);
    }
  }
}

// ---------------- Plan D fallback (tiny ws): per-edge recompute ----------------

static __device__ __forceinline__ float dotcol(const float* __restrict__ Wm, float val, int lane) {
  float acc = 0.f;
  for (int i = 0; i < 64; i++) acc = fmaf(__shfl(val, i), Wm[i * 64 + lane], acc);
  return acc;
}

template <typename TIN, typename TOUT>
__global__ void k_edge_d(const int* __restrict__ row_ptr, const int* __restrict__ stb,
                         const float* __restrict__ wbuf, int l, const TIN* __restrict__ emb_in,
                         TOUT* __restrict__ emb_out) {
  __shared__ float sab[80];
  int tid = threadIdx.x;
  int lane = tid & 63;
  int w = tid >> 6;
  int r = blockIdx.x * 4 + w;
  int hh = lane >> 3;
  if (tid < 80) {
    float a = wbuf[W_ABIN + l * 80 + tid];
    sab[tid] = (a > 0.f) ? a : 0.2f * a;
  }
  __syncthreads();
  const float* pwt = wbuf + W_APW + l * 8192;
  const float* pwb = pwt + 4096;
  const float* aw = wbuf + W_AW + l * 4096;
  const float* rw = wbuf + W_RW + l * 4096;

  float ev = ldv(emb_in, (size_t)r * 64 + lane);
  float xh = wbuf[W_APB + l * 64 + lane];
  float res = wbuf[W_RB + l * 64 + lane];
  for (int i = 0; i < 64; i++) {
    float e = __shfl(ev, i);
    xh = fmaf(e, pwt[i * 64 + lane], xh);
    res = fmaf(e, rw[i * 64 + lane], res);
  }
  res = fmaxf(res, 0.f);
  float av = wbuf[W_AVEC + l * 64 + lane];
  float abl = wbuf[W_AB + l * 64 + lane];

  int beg = (r == 0) ? 0 : row_ptr[r - 1];
  int end = row_ptr[r];
  float num = 0.f, den = 0.f;
  for (int j = beg; j < end; j++) {
    int p = stb[j];
    int t = p & 0xFFFF;
    float tv = ldv(emb_in, (size_t)t * 64 + lane);
    float z = xh + dotcol(pwb, tv, lane);
    z = (z > 0.f) ? z : 0.2f * z;
    float v = z * av;
    v += __shfl_xor(v, 1);
    v += __shfl_xor(v, 2);
    v += __shfl_xor(v, 4);
    float e = __expf(v + sab[(p >> 16) * 8 + hh]);
    den += e;
    float mt = dotcol(aw, tv, lane) + abl;
    num = fmaf(mt, e, num);
  }
  stv(emb_out, (size_t)r * 64 + lane, fmaxf(num / (den + 1e-16f), 0.f) + res);
}

// ---------------- launch ----------------

extern "C" void kernel_launch(void* const* d_in, const int* in_sizes, int n_in,
                              void* d_out, int out_size, void* d_ws, size_t ws_size,
                              hipStream_t stream) {
  const unsigned int* trip_w = (const unsigned int*)d_in[0];
  const void* rel_emb = d_in[1];
  float* emb = (float*)d_out;

  char* ws = (char*)d_ws;
  int* flag = (int*)(ws + O_FLAG);
  float* wbuf = (float*)(ws + O_WBUF);
  int* row_ptr = (int*)(ws + O_ROWP);
  int* counts = (int*)(ws + O_CNTS);
  int* tmp = (int*)(ws + O_TMP);
  int* partial = (int*)(ws + O_PART);
  int* stb = (int*)(ws + O_STB);
  char* big = ws + O_BIG;

  hipMemsetAsync(counts, 0, R_NUM * sizeof(int), stream);
  k_detect<<<1, 64, 0, stream>>>(trip_w, (const unsigned short*)rel_emb, flag);
  k_wconv<<<(W_END + 255) / 256, 256, 0, stream>>>(d_in[2], d_in[3], d_in[4], d_in[5], d_in[6],
                                                   d_in[7], d_in[8], d_in[9], d_in[10], d_in[11],
                                                   flag, wbuf);
  int eb_blocks = (E_NUM + 255) / 256;
  k_hist<<<eb_blocks, 256, 0, stream>>>(trip_w, flag, counts);
  k_scan_a<<<40, 1024, 0, stream>>>(counts, tmp, partial);
  k_scan_c<<<40, 1024, 0, stream>>>(counts, tmp, partial, row_ptr);
  k_scatter<<<eb_blocks, 256, 0, stream>>>(trip_w, flag, row_ptr, stb);

  if (ws_size >= NEED_FULL) {
    float2* XMa = (float2*)big;
    float2* XMb = XMa + (size_t)R_NUM * 64;
    float2* HR = XMb + (size_t)R_NUM * 64;
    k_emb0xm<<<R_NUM / 16, 256, 0, stream>>>(rel_emb, flag, wbuf, emb, XMa, HR, 2);
    k_edge_full<true><<<R_NUM / 16, 256, 0, stream>>>(row_ptr, stb, XMa, HR, wbuf, 0, emb, XMb);
    k_edge_full<false><<<R_NUM / 16, 256, 0, stream>>>(row_ptr, stb, XMb, HR, wbuf, 1, emb,
                                                       nullptr);
  } else if (ws_size >= NEED_XM2) {
    float2* XMa = (float2*)big;
    float2* XMb = XMa + (size_t)R_NUM * 64;
    k_emb0xm<<<R_NUM / 16, 256, 0, stream>>>(rel_emb, flag, wbuf, emb, XMa, nullptr, 1);
    k_edge_f<true><<<R_NUM / 16, 256, 0, stream>>>(row_ptr, stb, XMa, wbuf, 0, emb, XMb);
    k_edge_f<false><<<R_NUM / 16, 256, 0, stream>>>(row_ptr, stb, XMb, wbuf, 1, emb, nullptr);
  } else if (ws_size >= NEED_XM1) {
    float2* XM = (float2*)big;
    k_emb0xm<<<R_NUM / 16, 256, 0, stream>>>(rel_emb, flag, wbuf, emb, XM, nullptr, 1);
    k_edge_f<false><<<R_NUM / 16, 256, 0, stream>>>(row_ptr, stb, XM, wbuf, 0, emb, nullptr);
    k_xm<<<R_NUM / 16, 256, 0, stream>>>(emb, wbuf, 1, XM);
    k_edge_f<false><<<R_NUM / 16, 256, 0, stream>>>(row_ptr, stb, XM, wbuf, 1, emb, nullptr);
  } else {
    k_emb0xm<<<R_NUM / 16, 256, 0, stream>>>(rel_emb, flag, wbuf, emb, nullptr, nullptr, 0);
    bf16* embB = (bf16*)big;
    k_edge_d<float, bf16><<<R_NUM / 4, 256, 0, stream>>>(row_ptr, stb, wbuf, 0, emb, embB);
    k_edge_d<bf16, float><<<R_NUM / 4, 256, 0, stream>>>(row_ptr, stb, wbuf, 1, embB, emb);
  }
}

// Round 9
// 359.506 us; speedup vs baseline: 1.3599x; 1.3599x over previous
//
#include <hip/hip_runtime.h>
#include <hip/hip_bf16.h>

typedef __hip_bfloat16 bf16;

#define R_NUM 40000
#define E_NUM 500000

// wbuf layout (f32 element offsets)
#define W_P1W 0
#define W_P1B 4096
#define W_APW 4160    // 2*128*64
#define W_APB 20544   // 2*64
#define W_ABIN 20672  // 2*10*8
#define W_AVEC 20832  // 2*8*8
#define W_AW 20960    // 2*64*64
#define W_AB 29152
#define W_RW 29280
#define W_RB 37472
#define W_END 37600

// ws byte offsets
#define O_FLAG 0
#define O_WBUF 256
#define O_ROWP 150784
#define O_CNTS 310784
#define O_TMP 470784
#define O_PART 634624
#define O_STB 635136
#define O_BIG 2635392  // stb + 64-int zero pad
#define XM_BYTES 20480000ull
#define NEED_XM2 (O_BIG + 2 * XM_BYTES)  // 43,595,392 (ws >= 64 MB proven in R8)
#define NEED_XM1 (O_BIG + 1 * XM_BYTES)

static __device__ __forceinline__ float b2f(bf16 x) { return __bfloat162float(x); }
static __device__ __forceinline__ float ldv(const float* p, size_t i) { return p[i]; }
static __device__ __forceinline__ float ldv(const bf16* p, size_t i) { return __bfloat162float(p[i]); }
static __device__ __forceinline__ void stv(float* p, size_t i, float v) { p[i] = v; }
static __device__ __forceinline__ void stv(bf16* p, size_t i, float v) { p[i] = __float2bfloat16(v); }

// ---------------- runtime dtype detection ----------------

__global__ void k_detect(const unsigned int* __restrict__ trip_w,
                         const unsigned short* __restrict__ emb_w, int* __restrict__ flag) {
  int lane = threadIdx.x;
  unsigned int acc = 0;
  for (int i = lane; i < 1024; i += 64) acc |= trip_w[2 * i + 1];
  int votes = 0;
  for (int i = lane; i < 2048; i += 64) {
    unsigned short u = emb_w[2 * i];
    int ex = (u >> 7) & 0xFF;
    if (ex >= 90 && ex <= 130) votes++;
  }
  for (int off = 1; off < 64; off <<= 1) {
    acc |= __shfl_xor(acc, off);
    votes += __shfl_xor(votes, off);
  }
  if (lane == 0) {
    flag[0] = (acc == 0) ? 1 : 0;
    flag[1] = (votes < 1024) ? 1 : 0;
  }
}

// ---------------- weights -> f32 scratch ----------------

__global__ void k_wconv(const void* p1w, const void* p1b, const void* apw, const void* apb,
                        const void* abin, const void* avec, const void* aw, const void* ab,
                        const void* rw, const void* rb, const int* __restrict__ flag,
                        float* __restrict__ wbuf) {
  int i = blockIdx.x * 256 + threadIdx.x;
  if (i >= W_END) return;
  const void* src;
  int off;
  if (i < W_P1B) { src = p1w; off = i - W_P1W; }
  else if (i < W_APW) { src = p1b; off = i - W_P1B; }
  else if (i < W_APB) { src = apw; off = i - W_APW; }
  else if (i < W_ABIN) { src = apb; off = i - W_APB; }
  else if (i < W_AVEC) { src = abin; off = i - W_ABIN; }
  else if (i < W_AW) { src = avec; off = i - W_AVEC; }
  else if (i < W_AB) { src = aw; off = i - W_AW; }
  else if (i < W_RW) { src = ab; off = i - W_AB; }
  else if (i < W_RB) { src = rw; off = i - W_RW; }
  else { src = rb; off = i - W_RB; }
  wbuf[i] = flag[1] ? ((const float*)src)[off] : b2f(((const bf16*)src)[off]);
}

// ---------------- edge decode ----------------

static __device__ __forceinline__ void load_edge(const unsigned int* __restrict__ w, int e,
                                                 int i64, int& h, int& t, int& b) {
  if (i64) {
    h = (int)w[6 * e + 0];
    t = (int)w[6 * e + 2];
    b = (int)w[6 * e + 4];
  } else {
    h = (int)w[3 * e + 0];
    t = (int)w[3 * e + 1];
    b = (int)w[3 * e + 2];
  }
}

// ---------------- counting sort by head ----------------

__global__ void k_hist(const unsigned int* __restrict__ trip_w, const int* __restrict__ flag,
                       int* __restrict__ counts) {
  int e = blockIdx.x * 256 + threadIdx.x;
  if (e >= E_NUM) return;
  int h, t, b;
  load_edge(trip_w, e, flag[0], h, t, b);
  atomicAdd(&counts[h], 1);
}

__global__ void k_scan_a(const int* __restrict__ counts, int* __restrict__ tmp,
                         int* __restrict__ partial) {
  __shared__ int sd[1024];
  int tid = threadIdx.x;
  int idx = blockIdx.x * 1024 + tid;
  int v = (idx < R_NUM) ? counts[idx] : 0;
  sd[tid] = v;
  __syncthreads();
  for (int off = 1; off < 1024; off <<= 1) {
    int t = (tid >= off) ? sd[tid - off] : 0;
    __syncthreads();
    sd[tid] += t;
    __syncthreads();
  }
  if (idx < R_NUM) tmp[idx] = sd[tid];
  if (tid == 1023) partial[blockIdx.x] = sd[1023];
}

__global__ void k_scan_c(const int* __restrict__ counts, const int* __restrict__ tmp,
                         const int* __restrict__ partial, int* __restrict__ row_ptr) {
  __shared__ int soff;
  if (threadIdx.x < 64) {
    int lane = threadIdx.x;
    int p = (lane < (int)blockIdx.x) ? partial[lane] : 0;  // gridDim 40 <= 64
    for (int d = 1; d < 64; d <<= 1) p += __shfl_xor(p, d);
    if (lane == 0) soff = p;
  }
  __syncthreads();
  int idx = blockIdx.x * 1024 + threadIdx.x;
  if (idx < R_NUM) row_ptr[idx] = tmp[idx] - counts[idx] + soff;
}

// scatter bumps row_ptr: afterwards row_ptr[r] == end(r); beg(r) = r ? row_ptr[r-1] : 0
__global__ void k_scatter(const unsigned int* __restrict__ trip_w, const int* __restrict__ flag,
                          int* __restrict__ row_ptr, int* __restrict__ stb) {
  int e = blockIdx.x * 256 + threadIdx.x;
  if (e >= E_NUM) return;
  int h, t, b;
  load_edge(trip_w, e, flag[0], h, t, b);
  int pos = atomicAdd(&row_ptr[h], 1);
  stb[pos] = (t & 0xFFFF) | (b << 16);
}

// ---------------- fused emb0 (+ layer-0 XM) ----------------

__global__ void k_emb0xm(const void* __restrict__ A, const int* __restrict__ flag,
                         const float* __restrict__ wbuf, float* __restrict__ emb,
                         float2* __restrict__ XM, int write_xm) {
  int j = threadIdx.x & 63;
  int g = threadIdx.x >> 6;
  int r0 = blockIdx.x * 16 + g * 4;
  int f32 = flag[1];
  __shared__ float sA[16][64];
  for (int k = threadIdx.x; k < 1024; k += 256) {
    int rr = k >> 6, cc = k & 63;
    size_t idx = (size_t)(blockIdx.x * 16 + rr) * 64 + cc;
    sA[rr][cc] = f32 ? ((const float*)A)[idx] : b2f(((const bf16*)A)[idx]);
  }
  __syncthreads();
  const float* W = wbuf + W_P1W;
  float a[4] = {0.f, 0.f, 0.f, 0.f};
  int base = g * 4;
  for (int i = 0; i < 64; i++) {
    float w = W[i * 64 + j];
#pragma unroll
    for (int n = 0; n < 4; n++) a[n] = fmaf(sA[base + n][i], w, a[n]);
  }
  float bj = wbuf[W_P1B + j];
#pragma unroll
  for (int n = 0; n < 4; n++) {
    a[n] = fmaxf(a[n] + bj, 0.f);
    emb[(size_t)(r0 + n) * 64 + j] = a[n];
  }
  if (!write_xm) return;
  __syncthreads();
#pragma unroll
  for (int n = 0; n < 4; n++) sA[base + n][j] = a[n];
  __syncthreads();
  const float* pwb = wbuf + W_APW + 4096;
  const float* aw = wbuf + W_AW;
  float axt[4] = {0.f, 0.f, 0.f, 0.f};
  float amt[4] = {0.f, 0.f, 0.f, 0.f};
  for (int i = 0; i < 64; i++) {
    float wt = pwb[i * 64 + j];
    float wm = aw[i * 64 + j];
#pragma unroll
    for (int n = 0; n < 4; n++) {
      float e = sA[base + n][i];
      axt[n] = fmaf(e, wt, axt[n]);
      amt[n] = fmaf(e, wm, amt[n]);
    }
  }
  float abj = wbuf[W_AB + j];
#pragma unroll
  for (int n = 0; n < 4; n++)
    XM[(size_t)(r0 + n) * 64 + j] = make_float2(axt[n], amt[n] + abj);
}

// ---------------- standalone XM (XM1 fallback path) ----------------

__global__ void k_xm(const float* __restrict__ emb, const float* __restrict__ wbuf, int l,
                     float2* __restrict__ XM) {
  int j = threadIdx.x & 63;
  int g = threadIdx.x >> 6;
  int r0 = blockIdx.x * 16 + g * 4;
  __shared__ float sE[16][64];
  for (int k = threadIdx.x; k < 1024; k += 256) {
    int rr = k >> 6, cc = k & 63;
    sE[rr][cc] = emb[(size_t)(blockIdx.x * 16 + rr) * 64 + cc];
  }
  __syncthreads();
  const float* pwb = wbuf + W_APW + l * 8192 + 4096;
  const float* aw = wbuf + W_AW + l * 4096;
  float axt[4] = {0.f, 0.f, 0.f, 0.f};
  float amt[4] = {0.f, 0.f, 0.f, 0.f};
  int base = g * 4;
  for (int i = 0; i < 64; i++) {
    float wt = pwb[i * 64 + j];
    float wm = aw[i * 64 + j];
#pragma unroll
    for (int n = 0; n < 4; n++) {
      float e = sE[base + n][i];
      axt[n] = fmaf(e, wt, axt[n]);
      amt[n] = fmaf(e, wm, amt[n]);
    }
  }
  float abj = wbuf[W_AB + l * 64 + j];
#pragma unroll
  for (int n = 0; n < 4; n++)
    XM[(size_t)(r0 + n) * 64 + j] = make_float2(axt[n], amt[n] + abj);
}

// ---------------- edge kernel: branch-free window-16 gather ----------------
// stb is padded with 64 zero entries (t=0, b=0 -> valid XM row 0); window loads
// are unconditional straight-line code, masking happens in the consume phase.
// beg/end go through readfirstlane so descriptor loads are scalar.

template <bool WXM>
__global__ void __launch_bounds__(256, 4) k_edge_f(
    const int* __restrict__ row_ptr, const int* __restrict__ stb, const float2* __restrict__ XM,
    const float* __restrict__ wbuf, int l, float* __restrict__ emb, float2* __restrict__ XMout) {
  __shared__ float sab[80];
  int tid = threadIdx.x;
  int lane = tid & 63;
  int w = tid >> 6;
  int hh = lane >> 3;
  if (tid < 80) {
    float a = wbuf[W_ABIN + l * 80 + tid];
    sab[tid] = (a > 0.f) ? a : 0.2f * a;
  }
  __syncthreads();

  const float* pwt = wbuf + W_APW + l * 8192;
  const float* rwp = wbuf + W_RW + l * 4096;
  const float* pwb1 = wbuf + W_APW + 8192 + 4096;
  const float* aw1 = wbuf + W_AW + 4096;
  float av = wbuf[W_AVEC + l * 64 + lane];
  float xh0 = wbuf[W_APB + l * 64 + lane];
  float res0 = wbuf[W_RB + l * 64 + lane];
  float ab1 = WXM ? wbuf[W_AB + 64 + lane] : 0.f;

  int r0 = blockIdx.x * 16 + w * 4;
  for (int rr = 0; rr < 4; rr++) {
    int r = r0 + rr;
    float ev = emb[(size_t)r * 64 + lane];
    float xh = xh0, res = res0;
#pragma unroll 16
    for (int i = 0; i < 64; i++) {
      float e = __shfl(ev, i);
      xh = fmaf(e, pwt[i * 64 + lane], xh);
      res = fmaf(e, rwp[i * 64 + lane], res);
    }
    res = fmaxf(res, 0.f);

    int beg = (r == 0) ? 0 : row_ptr[r - 1];
    int end = row_ptr[r];
    beg = __builtin_amdgcn_readfirstlane(beg);
    end = __builtin_amdgcn_readfirstlane(end);

    float num = 0.f, den = 0.f;
    for (int j = beg; j < end; j += 16) {
      int pk[16];
      float2 xmv[16];
#pragma unroll
      for (int k = 0; k < 16; k++) pk[k] = stb[j + k];  // scalar loads (uniform addr)
#pragma unroll
      for (int k = 0; k < 16; k++)
        xmv[k] = XM[(size_t)(pk[k] & 0xFFFF) * 64 + lane];  // 16 gathers in flight
#pragma unroll
      for (int k = 0; k < 16; k++) {
        float z = xh + xmv[k].x;
        z = (z > 0.f) ? z : 0.2f * z;
        float v = z * av;
        v += __shfl_xor(v, 1);
        v += __shfl_xor(v, 2);
        v += __shfl_xor(v, 4);
        float e = __expf(v + sab[(pk[k] >> 16) * 8 + hh]);
        e = (j + k < end) ? e : 0.f;
        den += e;
        num = fmaf(xmv[k].y, e, num);
      }
    }

    float o = fmaxf(num / (den + 1e-16f), 0.f) + res;
    emb[(size_t)r * 64 + lane] = o;
    if (WXM) {
      float xt = 0.f, mt = ab1;
#pragma unroll 16
      for (int i = 0; i < 64; i++) {
        float e = __shfl(o, i);
        xt = fmaf(e, pwb1[i * 64 + lane], xt);
        mt = fmaf(e, aw1[i * 64 + lane], mt);
      }
      XMout[(size_t)r * 64 + lane] = make_float2(xt, mt);
    }
  }
}

// ---------------- Plan D fallback (tiny ws): per-edge recompute ----------------

static __device__ __forceinline__ float dotcol(const float* __restrict__ Wm, float val, int lane) {
  float acc = 0.f;
  for (int i = 0; i < 64; i++) acc = fmaf(__shfl(val, i), Wm[i * 64 + lane], acc);
  return acc;
}

template <typename TIN, typename TOUT>
__global__ void k_edge_d(const int* __restrict__ row_ptr, const int* __restrict__ stb,
                         const float* __restrict__ wbuf, int l, const TIN* __restrict__ emb_in,
                         TOUT* __restrict__ emb_out) {
  __shared__ float sab[80];
  int tid = threadIdx.x;
  int lane = tid & 63;
  int w = tid >> 6;
  int r = blockIdx.x * 4 + w;
  int hh = lane >> 3;
  if (tid < 80) {
    float a = wbuf[W_ABIN + l * 80 + tid];
    sab[tid] = (a > 0.f) ? a : 0.2f * a;
  }
  __syncthreads();
  const float* pwt = wbuf + W_APW + l * 8192;
  const float* pwb = pwt + 4096;
  const float* aw = wbuf + W_AW + l * 4096;
  const float* rw = wbuf + W_RW + l * 4096;

  float ev = ldv(emb_in, (size_t)r * 64 + lane);
  float xh = wbuf[W_APB + l * 64 + lane];
  float res = wbuf[W_RB + l * 64 + lane];
  for (int i = 0; i < 64; i++) {
    float e = __shfl(ev, i);
    xh = fmaf(e, pwt[i * 64 + lane], xh);
    res = fmaf(e, rw[i * 64 + lane], res);
  }
  res = fmaxf(res, 0.f);
  float av = wbuf[W_AVEC + l * 64 + lane];
  float abl = wbuf[W_AB + l * 64 + lane];

  int beg = (r == 0) ? 0 : row_ptr[r - 1];
  int end = row_ptr[r];
  float num = 0.f, den = 0.f;
  for (int j = beg; j < end; j++) {
    int p = stb[j];
    int t = p & 0xFFFF;
    float tv = ldv(emb_in, (size_t)t * 64 + lane);
    float z = xh + dotcol(pwb, tv, lane);
    z = (z > 0.f) ? z : 0.2f * z;
    float v = z * av;
    v += __shfl_xor(v, 1);
    v += __shfl_xor(v, 2);
    v += __shfl_xor(v, 4);
    float e = __expf(v + sab[(p >> 16) * 8 + hh]);
    den += e;
    float mt = dotcol(aw, tv, lane) + abl;
    num = fmaf(mt, e, num);
  }
  stv(emb_out, (size_t)r * 64 + lane, fmaxf(num / (den + 1e-16f), 0.f) + res);
}

// ---------------- launch ----------------

extern "C" void kernel_launch(void* const* d_in, const int* in_sizes, int n_in,
                              void* d_out, int out_size, void* d_ws, size_t ws_size,
                              hipStream_t stream) {
  const unsigned int* trip_w = (const unsigned int*)d_in[0];
  const void* rel_emb = d_in[1];
  float* emb = (float*)d_out;

  char* ws = (char*)d_ws;
  int* flag = (int*)(ws + O_FLAG);
  float* wbuf = (float*)(ws + O_WBUF);
  int* row_ptr = (int*)(ws + O_ROWP);
  int* counts = (int*)(ws + O_CNTS);
  int* tmp = (int*)(ws + O_TMP);
  int* partial = (int*)(ws + O_PART);
  int* stb = (int*)(ws + O_STB);
  char* big = ws + O_BIG;

  hipMemsetAsync(counts, 0, R_NUM * sizeof(int), stream);
  hipMemsetAsync(stb + E_NUM, 0, 64 * sizeof(int), stream);  // window over-read pad
  k_detect<<<1, 64, 0, stream>>>(trip_w, (const unsigned short*)rel_emb, flag);
  k_wconv<<<(W_END + 255) / 256, 256, 0, stream>>>(d_in[2], d_in[3], d_in[4], d_in[5], d_in[6],
                                                   d_in[7], d_in[8], d_in[9], d_in[10], d_in[11],
                                                   flag, wbuf);
  int eb_blocks = (E_NUM + 255) / 256;
  k_hist<<<eb_blocks, 256, 0, stream>>>(trip_w, flag, counts);
  k_scan_a<<<40, 1024, 0, stream>>>(counts, tmp, partial);
  k_scan_c<<<40, 1024, 0, stream>>>(counts, tmp, partial, row_ptr);
  k_scatter<<<eb_blocks, 256, 0, stream>>>(trip_w, flag, row_ptr, stb);

  if (ws_size >= NEED_XM2) {
    float2* XMa = (float2*)big;
    float2* XMb = XMa + (size_t)R_NUM * 64;
    k_emb0xm<<<R_NUM / 16, 256, 0, stream>>>(rel_emb, flag, wbuf, emb, XMa, 1);
    k_edge_f<true><<<R_NUM / 16, 256, 0, stream>>>(row_ptr, stb, XMa, wbuf, 0, emb, XMb);
    k_edge_f<false><<<R_NUM / 16, 256, 0, stream>>>(row_ptr, stb, XMb, wbuf, 1, emb, nullptr);
  } else if (ws_size >= NEED_XM1) {
    float2* XM = (float2*)big;
    k_emb0xm<<<R_NUM / 16, 256, 0, stream>>>(rel_emb, flag, wbuf, emb, XM, 1);
    k_edge_f<false><<<R_NUM / 16, 256, 0, stream>>>(row_ptr, stb, XM, wbuf, 0, emb, nullptr);
    k_xm<<<R_NUM / 16, 256, 0, stream>>>(emb, wbuf, 1, XM);
    k_edge_f<false><<<R_NUM / 16, 256, 0, stream>>>(row_ptr, stb, XM, wbuf, 1, emb, nullptr);
  } else {
    k_emb0xm<<<R_NUM / 16, 256, 0, stream>>>(rel_emb, flag, wbuf, emb, nullptr, 0);
    bf16* embB = (bf16*)big;
    k_edge_d<float, bf16><<<R_NUM / 4, 256, 0, stream>>>(row_ptr, stb, wbuf, 0, emb, embB);
    k_edge_d<bf16, float><<<R_NUM / 4, 256, 0, stream>>>(row_ptr, stb, wbuf, 1, embB, emb);
  }
}

// Round 10
// 307.065 us; speedup vs baseline: 1.5921x; 1.1708x over previous
//
#include <hip/hip_runtime.h>
#include <hip/hip_bf16.h>

typedef __hip_bfloat16 bf16;

#define R_NUM 40000
#define E_NUM 500000

// wbuf layout (f32 element offsets)
#define W_P1W 0
#define W_P1B 4096
#define W_APW 4160    // 2*128*64
#define W_APB 20544   // 2*64
#define W_ABIN 20672  // 2*10*8
#define W_AVEC 20832  // 2*8*8
#define W_AW 20960    // 2*64*64
#define W_AB 29152
#define W_RW 29280
#define W_RB 37472
#define W_END 37600

// ws byte offsets
#define O_FLAG 0
#define O_WBUF 256
#define O_ROWP 150784
#define O_CNTS 310784
#define O_TMP 470784
#define O_PART 634624
#define O_STB 635136
#define O_BIG 2635392  // stb + 64-int zero pad
#define XM_BYTES 20480000ull
#define NEED_LEAN (O_BIG + 2 * XM_BYTES)  // 43,595,392: XM + HR (proven to fit)
#define NEED_XM1 (O_BIG + 1 * XM_BYTES)

static __device__ __forceinline__ float b2f(bf16 x) { return __bfloat162float(x); }
static __device__ __forceinline__ float ldv(const float* p, size_t i) { return p[i]; }
static __device__ __forceinline__ float ldv(const bf16* p, size_t i) { return __bfloat162float(p[i]); }
static __device__ __forceinline__ void stv(float* p, size_t i, float v) { p[i] = v; }
static __device__ __forceinline__ void stv(bf16* p, size_t i, float v) { p[i] = __float2bfloat16(v); }

// ---------------- runtime dtype detection ----------------

__global__ void k_detect(const unsigned int* __restrict__ trip_w,
                         const unsigned short* __restrict__ emb_w, int* __restrict__ flag) {
  int lane = threadIdx.x;
  unsigned int acc = 0;
  for (int i = lane; i < 1024; i += 64) acc |= trip_w[2 * i + 1];
  int votes = 0;
  for (int i = lane; i < 2048; i += 64) {
    unsigned short u = emb_w[2 * i];
    int ex = (u >> 7) & 0xFF;
    if (ex >= 90 && ex <= 130) votes++;
  }
  for (int off = 1; off < 64; off <<= 1) {
    acc |= __shfl_xor(acc, off);
    votes += __shfl_xor(votes, off);
  }
  if (lane == 0) {
    flag[0] = (acc == 0) ? 1 : 0;
    flag[1] = (votes < 1024) ? 1 : 0;
  }
}

// ---------------- weights -> f32 scratch ----------------

__global__ void k_wconv(const void* p1w, const void* p1b, const void* apw, const void* apb,
                        const void* abin, const void* avec, const void* aw, const void* ab,
                        const void* rw, const void* rb, const int* __restrict__ flag,
                        float* __restrict__ wbuf) {
  int i = blockIdx.x * 256 + threadIdx.x;
  if (i >= W_END) return;
  const void* src;
  int off;
  if (i < W_P1B) { src = p1w; off = i - W_P1W; }
  else if (i < W_APW) { src = p1b; off = i - W_P1B; }
  else if (i < W_APB) { src = apw; off = i - W_APW; }
  else if (i < W_ABIN) { src = apb; off = i - W_APB; }
  else if (i < W_AVEC) { src = abin; off = i - W_ABIN; }
  else if (i < W_AW) { src = avec; off = i - W_AVEC; }
  else if (i < W_AB) { src = aw; off = i - W_AW; }
  else if (i < W_RW) { src = ab; off = i - W_AB; }
  else if (i < W_RB) { src = rw; off = i - W_RW; }
  else { src = rb; off = i - W_RB; }
  wbuf[i] = flag[1] ? ((const float*)src)[off] : b2f(((const bf16*)src)[off]);
}

// ---------------- edge decode ----------------

static __device__ __forceinline__ void load_edge(const unsigned int* __restrict__ w, int e,
                                                 int i64, int& h, int& t, int& b) {
  if (i64) {
    h = (int)w[6 * e + 0];
    t = (int)w[6 * e + 2];
    b = (int)w[6 * e + 4];
  } else {
    h = (int)w[3 * e + 0];
    t = (int)w[3 * e + 1];
    b = (int)w[3 * e + 2];
  }
}

// ---------------- counting sort by head ----------------

__global__ void k_hist(const unsigned int* __restrict__ trip_w, const int* __restrict__ flag,
                       int* __restrict__ counts) {
  int e = blockIdx.x * 256 + threadIdx.x;
  if (e >= E_NUM) return;
  int h, t, b;
  load_edge(trip_w, e, flag[0], h, t, b);
  atomicAdd(&counts[h], 1);
}

__global__ void k_scan_a(const int* __restrict__ counts, int* __restrict__ tmp,
                         int* __restrict__ partial) {
  __shared__ int sd[1024];
  int tid = threadIdx.x;
  int idx = blockIdx.x * 1024 + tid;
  int v = (idx < R_NUM) ? counts[idx] : 0;
  sd[tid] = v;
  __syncthreads();
  for (int off = 1; off < 1024; off <<= 1) {
    int t = (tid >= off) ? sd[tid - off] : 0;
    __syncthreads();
    sd[tid] += t;
    __syncthreads();
  }
  if (idx < R_NUM) tmp[idx] = sd[tid];
  if (tid == 1023) partial[blockIdx.x] = sd[1023];
}

__global__ void k_scan_c(const int* __restrict__ counts, const int* __restrict__ tmp,
                         const int* __restrict__ partial, int* __restrict__ row_ptr) {
  __shared__ int soff;
  if (threadIdx.x < 64) {
    int lane = threadIdx.x;
    int p = (lane < (int)blockIdx.x) ? partial[lane] : 0;  // gridDim 40 <= 64
    for (int d = 1; d < 64; d <<= 1) p += __shfl_xor(p, d);
    if (lane == 0) soff = p;
  }
  __syncthreads();
  int idx = blockIdx.x * 1024 + threadIdx.x;
  if (idx < R_NUM) row_ptr[idx] = tmp[idx] - counts[idx] + soff;
}

// scatter bumps row_ptr: afterwards row_ptr[r] == end(r); beg(r) = r ? row_ptr[r-1] : 0
__global__ void k_scatter(const unsigned int* __restrict__ trip_w, const int* __restrict__ flag,
                          int* __restrict__ row_ptr, int* __restrict__ stb) {
  int e = blockIdx.x * 256 + threadIdx.x;
  if (e >= E_NUM) return;
  int h, t, b;
  load_edge(trip_w, e, flag[0], h, t, b);
  int pos = atomicAdd(&row_ptr[h], 1);
  stb[pos] = (t & 0xFFFF) | (b << 16);
}

// ---------------- fused emb0 (+XM l0) (+HR l0) ----------------
// mode 0: emb only; 1: +XM; 2: +XM +HR

__global__ void k_emb0xm(const void* __restrict__ A, const int* __restrict__ flag,
                         const float* __restrict__ wbuf, float* __restrict__ emb,
                         float2* __restrict__ XM, float2* __restrict__ HR, int mode) {
  int j = threadIdx.x & 63;
  int g = threadIdx.x >> 6;
  int r0 = blockIdx.x * 16 + g * 4;
  int f32 = flag[1];
  __shared__ float sA[16][64];
  for (int k = threadIdx.x; k < 1024; k += 256) {
    int rr = k >> 6, cc = k & 63;
    size_t idx = (size_t)(blockIdx.x * 16 + rr) * 64 + cc;
    sA[rr][cc] = f32 ? ((const float*)A)[idx] : b2f(((const bf16*)A)[idx]);
  }
  __syncthreads();
  const float* W = wbuf + W_P1W;
  float a[4] = {0.f, 0.f, 0.f, 0.f};
  int base = g * 4;
  for (int i = 0; i < 64; i++) {
    float w = W[i * 64 + j];
#pragma unroll
    for (int n = 0; n < 4; n++) a[n] = fmaf(sA[base + n][i], w, a[n]);
  }
  float bj = wbuf[W_P1B + j];
#pragma unroll
  for (int n = 0; n < 4; n++) {
    a[n] = fmaxf(a[n] + bj, 0.f);
    emb[(size_t)(r0 + n) * 64 + j] = a[n];
  }
  if (mode == 0) return;
  __syncthreads();
#pragma unroll
  for (int n = 0; n < 4; n++) sA[base + n][j] = a[n];
  __syncthreads();
  {
    const float* pwb = wbuf + W_APW + 4096;  // layer-0 bottom proj
    const float* aw = wbuf + W_AW;
    float axt[4] = {0.f, 0.f, 0.f, 0.f};
    float amt[4] = {0.f, 0.f, 0.f, 0.f};
    for (int i = 0; i < 64; i++) {
      float wt = pwb[i * 64 + j];
      float wm = aw[i * 64 + j];
#pragma unroll
      for (int n = 0; n < 4; n++) {
        float e = sA[base + n][i];
        axt[n] = fmaf(e, wt, axt[n]);
        amt[n] = fmaf(e, wm, amt[n]);
      }
    }
    float abj = wbuf[W_AB + j];
#pragma unroll
    for (int n = 0; n < 4; n++)
      XM[(size_t)(r0 + n) * 64 + j] = make_float2(axt[n], amt[n] + abj);
  }
  if (mode < 2) return;
  {
    const float* pwt = wbuf + W_APW;  // layer-0 top proj
    const float* rw = wbuf + W_RW;
    float axh[4] = {0.f, 0.f, 0.f, 0.f};
    float ars[4] = {0.f, 0.f, 0.f, 0.f};
    for (int i = 0; i < 64; i++) {
      float wh = pwt[i * 64 + j];
      float wr = rw[i * 64 + j];
#pragma unroll
      for (int n = 0; n < 4; n++) {
        float e = sA[base + n][i];
        axh[n] = fmaf(e, wh, axh[n]);
        ars[n] = fmaf(e, wr, ars[n]);
      }
    }
    float pbj = wbuf[W_APB + j];
    float rbj = wbuf[W_RB + j];
#pragma unroll
    for (int n = 0; n < 4; n++)
      HR[(size_t)(r0 + n) * 64 + j] = make_float2(axh[n] + pbj, fmaxf(ars[n] + rbj, 0.f));
  }
}

// ---------------- node-parallel XM+HR for layer l ----------------

__global__ void k_xmhr(const float* __restrict__ emb, const float* __restrict__ wbuf, int l,
                       float2* __restrict__ XM, float2* __restrict__ HR) {
  int j = threadIdx.x & 63;
  int g = threadIdx.x >> 6;
  int r0 = blockIdx.x * 16 + g * 4;
  __shared__ float sE[16][64];
  for (int k = threadIdx.x; k < 1024; k += 256) {
    int rr = k >> 6, cc = k & 63;
    sE[rr][cc] = emb[(size_t)(blockIdx.x * 16 + rr) * 64 + cc];
  }
  __syncthreads();
  const float* pwt = wbuf + W_APW + l * 8192;
  const float* pwb = pwt + 4096;
  const float* aw = wbuf + W_AW + l * 4096;
  const float* rw = wbuf + W_RW + l * 4096;
  float axt[4] = {0.f, 0.f, 0.f, 0.f};
  float amt[4] = {0.f, 0.f, 0.f, 0.f};
  float axh[4] = {0.f, 0.f, 0.f, 0.f};
  float ars[4] = {0.f, 0.f, 0.f, 0.f};
  int base = g * 4;
  for (int i = 0; i < 64; i++) {
    float wt = pwb[i * 64 + j];
    float wm = aw[i * 64 + j];
    float wh = pwt[i * 64 + j];
    float wr = rw[i * 64 + j];
#pragma unroll
    for (int n = 0; n < 4; n++) {
      float e = sE[base + n][i];
      axt[n] = fmaf(e, wt, axt[n]);
      amt[n] = fmaf(e, wm, amt[n]);
      axh[n] = fmaf(e, wh, axh[n]);
      ars[n] = fmaf(e, wr, ars[n]);
    }
  }
  float abj = wbuf[W_AB + l * 64 + j];
  float pbj = wbuf[W_APB + l * 64 + j];
  float rbj = wbuf[W_RB + l * 64 + j];
#pragma unroll
  for (int n = 0; n < 4; n++) {
    XM[(size_t)(r0 + n) * 64 + j] = make_float2(axt[n], amt[n] + abj);
    HR[(size_t)(r0 + n) * 64 + j] = make_float2(axh[n] + pbj, fmaxf(ars[n] + rbj, 0.f));
  }
}

// ---------------- lean edge kernel: NO weight streaming ----------------
// One row per wave. HR gives (xh, relu'd res) in one 8B load; branch-free
// window-16 gathers (stb zero-padded); scalar row bounds via readfirstlane.

__global__ void __launch_bounds__(256, 4) k_edge_lean(
    const int* __restrict__ row_ptr, const int* __restrict__ stb, const float2* __restrict__ XM,
    const float2* __restrict__ HR, const float* __restrict__ wbuf, int l,
    float* __restrict__ emb) {
  __shared__ float sab[80];
  int tid = threadIdx.x;
  int lane = tid & 63;
  int w = tid >> 6;
  int hh = lane >> 3;
  if (tid < 80) {
    float a = wbuf[W_ABIN + l * 80 + tid];
    sab[tid] = (a > 0.f) ? a : 0.2f * a;
  }
  __syncthreads();
  float av = wbuf[W_AVEC + l * 64 + lane];

  int r = blockIdx.x * 4 + w;
  float2 hr = HR[(size_t)r * 64 + lane];
  int beg = (r == 0) ? 0 : row_ptr[r - 1];
  int end = row_ptr[r];
  beg = __builtin_amdgcn_readfirstlane(beg);
  end = __builtin_amdgcn_readfirstlane(end);

  float xh = hr.x;
  float num = 0.f, den = 0.f;
  for (int j = beg; j < end; j += 16) {
    int pk[16];
    float2 xmv[16];
#pragma unroll
    for (int k = 0; k < 16; k++) pk[k] = stb[j + k];  // scalar loads
#pragma unroll
    for (int k = 0; k < 16; k++)
      xmv[k] = XM[(size_t)(pk[k] & 0xFFFF) * 64 + lane];  // 16 gathers in flight
#pragma unroll
    for (int k = 0; k < 16; k++) {
      float z = xh + xmv[k].x;
      z = (z > 0.f) ? z : 0.2f * z;
      float v = z * av;
      v += __shfl_xor(v, 1);
      v += __shfl_xor(v, 2);
      v += __shfl_xor(v, 4);
      float e = __expf(v + sab[(pk[k] >> 16) * 8 + hh]);
      e = (j + k < end) ? e : 0.f;
      den += e;
      num = fmaf(xmv[k].y, e, num);
    }
  }
  emb[(size_t)r * 64 + lane] = fmaxf(num / (den + 1e-16f), 0.f) + hr.y;
}

// ---------------- XM1 fallback: R9 edge kernel (in-kernel preamble) ----------------

__global__ void k_xm(const float* __restrict__ emb, const float* __restrict__ wbuf, int l,
                     float2* __restrict__ XM) {
  int j = threadIdx.x & 63;
  int g = threadIdx.x >> 6;
  int r0 = blockIdx.x * 16 + g * 4;
  __shared__ float sE[16][64];
  for (int k = threadIdx.x; k < 1024; k += 256) {
    int rr = k >> 6, cc = k & 63;
    sE[rr][cc] = emb[(size_t)(blockIdx.x * 16 + rr) * 64 + cc];
  }
  __syncthreads();
  const float* pwb = wbuf + W_APW + l * 8192 + 4096;
  const float* aw = wbuf + W_AW + l * 4096;
  float axt[4] = {0.f, 0.f, 0.f, 0.f};
  float amt[4] = {0.f, 0.f, 0.f, 0.f};
  int base = g * 4;
  for (int i = 0; i < 64; i++) {
    float wt = pwb[i * 64 + j];
    float wm = aw[i * 64 + j];
#pragma unroll
    for (int n = 0; n < 4; n++) {
      float e = sE[base + n][i];
      axt[n] = fmaf(e, wt, axt[n]);
      amt[n] = fmaf(e, wm, amt[n]);
    }
  }
  float abj = wbuf[W_AB + l * 64 + j];
#pragma unroll
  for (int n = 0; n < 4; n++)
    XM[(size_t)(r0 + n) * 64 + j] = make_float2(axt[n], amt[n] + abj);
}

__global__ void __launch_bounds__(256, 4) k_edge_f(
    const int* __restrict__ row_ptr, const int* __restrict__ stb, const float2* __restrict__ XM,
    const float* __restrict__ wbuf, int l, float* __restrict__ emb) {
  __shared__ float sab[80];
  int tid = threadIdx.x;
  int lane = tid & 63;
  int w = tid >> 6;
  int hh = lane >> 3;
  if (tid < 80) {
    float a = wbuf[W_ABIN + l * 80 + tid];
    sab[tid] = (a > 0.f) ? a : 0.2f * a;
  }
  __syncthreads();

  const float* pwt = wbuf + W_APW + l * 8192;
  const float* rwp = wbuf + W_RW + l * 4096;
  float av = wbuf[W_AVEC + l * 64 + lane];
  float xh0 = wbuf[W_APB + l * 64 + lane];
  float res0 = wbuf[W_RB + l * 64 + lane];

  int r0 = blockIdx.x * 16 + w * 4;
  for (int rr = 0; rr < 4; rr++) {
    int r = r0 + rr;
    float ev = emb[(size_t)r * 64 + lane];
    float xh = xh0, res = res0;
#pragma unroll 16
    for (int i = 0; i < 64; i++) {
      float e = __shfl(ev, i);
      xh = fmaf(e, pwt[i * 64 + lane], xh);
      res = fmaf(e, rwp[i * 64 + lane], res);
    }
    res = fmaxf(res, 0.f);

    int beg = (r == 0) ? 0 : row_ptr[r - 1];
    int end = row_ptr[r];
    beg = __builtin_amdgcn_readfirstlane(beg);
    end = __builtin_amdgcn_readfirstlane(end);

    float num = 0.f, den = 0.f;
    for (int j = beg; j < end; j += 16) {
      int pk[16];
      float2 xmv[16];
#pragma unroll
      for (int k = 0; k < 16; k++) pk[k] = stb[j + k];
#pragma unroll
      for (int k = 0; k < 16; k++) xmv[k] = XM[(size_t)(pk[k] & 0xFFFF) * 64 + lane];
#pragma unroll
      for (int k = 0; k < 16; k++) {
        float z = xh + xmv[k].x;
        z = (z > 0.f) ? z : 0.2f * z;
        float v = z * av;
        v += __shfl_xor(v, 1);
        v += __shfl_xor(v, 2);
        v += __shfl_xor(v, 4);
        float e = __expf(v + sab[(pk[k] >> 16) * 8 + hh]);
        e = (j + k < end) ? e : 0.f;
        den += e;
        num = fmaf(xmv[k].y, e, num);
      }
    }
    emb[(size_t)r * 64 + lane] = fmaxf(num / (den + 1e-16f), 0.f) + res;
  }
}

// ---------------- Plan D fallback (tiny ws): per-edge recompute ----------------

static __device__ __forceinline__ float dotcol(const float* __restrict__ Wm, float val, int lane) {
  float acc = 0.f;
  for (int i = 0; i < 64; i++) acc = fmaf(__shfl(val, i), Wm[i * 64 + lane], acc);
  return acc;
}

template <typename TIN, typename TOUT>
__global__ void k_edge_d(const int* __restrict__ row_ptr, const int* __restrict__ stb,
                         const float* __restrict__ wbuf, int l, const TIN* __restrict__ emb_in,
                         TOUT* __restrict__ emb_out) {
  __shared__ float sab[80];
  int tid = threadIdx.x;
  int lane = tid & 63;
  int w = tid >> 6;
  int r = blockIdx.x * 4 + w;
  int hh = lane >> 3;
  if (tid < 80) {
    float a = wbuf[W_ABIN + l * 80 + tid];
    sab[tid] = (a > 0.f) ? a : 0.2f * a;
  }
  __syncthreads();
  const float* pwt = wbuf + W_APW + l * 8192;
  const float* pwb = pwt + 4096;
  const float* aw = wbuf + W_AW + l * 4096;
  const float* rw = wbuf + W_RW + l * 4096;

  float ev = ldv(emb_in, (size_t)r * 64 + lane);
  float xh = wbuf[W_APB + l * 64 + lane];
  float res = wbuf[W_RB + l * 64 + lane];
  for (int i = 0; i < 64; i++) {
    float e = __shfl(ev, i);
    xh = fmaf(e, pwt[i * 64 + lane], xh);
    res = fmaf(e, rw[i * 64 + lane], res);
  }
  res = fmaxf(res, 0.f);
  float av = wbuf[W_AVEC + l * 64 + lane];
  float abl = wbuf[W_AB + l * 64 + lane];

  int beg = (r == 0) ? 0 : row_ptr[r - 1];
  int end = row_ptr[r];
  float num = 0.f, den = 0.f;
  for (int j = beg; j < end; j++) {
    int p = stb[j];
    int t = p & 0xFFFF;
    float tv = ldv(emb_in, (size_t)t * 64 + lane);
    float z = xh + dotcol(pwb, tv, lane);
    z = (z > 0.f) ? z : 0.2f * z;
    float v = z * av;
    v += __shfl_xor(v, 1);
    v += __shfl_xor(v, 2);
    v += __shfl_xor(v, 4);
    float e = __expf(v + sab[(p >> 16) * 8 + hh]);
    den += e;
    float mt = dotcol(aw, tv, lane) + abl;
    num = fmaf(mt, e, num);
  }
  stv(emb_out, (size_t)r * 64 + lane, fmaxf(num / (den + 1e-16f), 0.f) + res);
}

// ---------------- launch ----------------

extern "C" void kernel_launch(void* const* d_in, const int* in_sizes, int n_in,
                              void* d_out, int out_size, void* d_ws, size_t ws_size,
                              hipStream_t stream) {
  const unsigned int* trip_w = (const unsigned int*)d_in[0];
  const void* rel_emb = d_in[1];
  float* emb = (float*)d_out;

  char* ws = (char*)d_ws;
  int* flag = (int*)(ws + O_FLAG);
  float* wbuf = (float*)(ws + O_WBUF);
  int* row_ptr = (int*)(ws + O_ROWP);
  int* counts = (int*)(ws + O_CNTS);
  int* tmp = (int*)(ws + O_TMP);
  int* partial = (int*)(ws + O_PART);
  int* stb = (int*)(ws + O_STB);
  char* big = ws + O_BIG;

  hipMemsetAsync(counts, 0, R_NUM * sizeof(int), stream);
  hipMemsetAsync(stb + E_NUM, 0, 64 * sizeof(int), stream);  // window over-read pad
  k_detect<<<1, 64, 0, stream>>>(trip_w, (const unsigned short*)rel_emb, flag);
  k_wconv<<<(W_END + 255) / 256, 256, 0, stream>>>(d_in[2], d_in[3], d_in[4], d_in[5], d_in[6],
                                                   d_in[7], d_in[8], d_in[9], d_in[10], d_in[11],
                                                   flag, wbuf);
  int eb_blocks = (E_NUM + 255) / 256;
  k_hist<<<eb_blocks, 256, 0, stream>>>(trip_w, flag, counts);
  k_scan_a<<<40, 1024, 0, stream>>>(counts, tmp, partial);
  k_scan_c<<<40, 1024, 0, stream>>>(counts, tmp, partial, row_ptr);
  k_scatter<<<eb_blocks, 256, 0, stream>>>(trip_w, flag, row_ptr, stb);

  if (ws_size >= NEED_LEAN) {
    float2* XM = (float2*)big;
    float2* HR = XM + (size_t)R_NUM * 64;
    k_emb0xm<<<R_NUM / 16, 256, 0, stream>>>(rel_emb, flag, wbuf, emb, XM, HR, 2);
    k_edge_lean<<<R_NUM / 4, 256, 0, stream>>>(row_ptr, stb, XM, HR, wbuf, 0, emb);
    k_xmhr<<<R_NUM / 16, 256, 0, stream>>>(emb, wbuf, 1, XM, HR);
    k_edge_lean<<<R_NUM / 4, 256, 0, stream>>>(row_ptr, stb, XM, HR, wbuf, 1, emb);
  } else if (ws_size >= NEED_XM1) {
    float2* XM = (float2*)big;
    k_emb0xm<<<R_NUM / 16, 256, 0, stream>>>(rel_emb, flag, wbuf, emb, XM, nullptr, 1);
    k_edge_f<<<R_NUM / 16, 256, 0, stream>>>(row_ptr, stb, XM, wbuf, 0, emb);
    k_xm<<<R_NUM / 16, 256, 0, stream>>>(emb, wbuf, 1, XM);
    k_edge_f<<<R_NUM / 16, 256, 0, stream>>>(row_ptr, stb, XM, wbuf, 1, emb);
  } else {
    k_emb0xm<<<R_NUM / 16, 256, 0, stream>>>(rel_emb, flag, wbuf, emb, nullptr, nullptr, 0);
    bf16* embB = (bf16*)big;
    k_edge_d<float, bf16><<<R_NUM / 4, 256, 0, stream>>>(row_ptr, stb, wbuf, 0, emb, embB);
    k_edge_d<bf16, float><<<R_NUM / 4, 256, 0, stream>>>(row_ptr, stb, wbuf, 1, embB, emb);
  }
}

// Round 11
// 275.251 us; speedup vs baseline: 1.7761x; 1.1156x over previous
//
#include <hip/hip_runtime.h>
#include <hip/hip_bf16.h>

typedef __hip_bfloat16 bf16;

#define R_NUM 40000
#define E_NUM 500000

// wbuf layout (f32 element offsets)
#define W_P1W 0
#define W_P1B 4096
#define W_APW 4160    // 2*128*64
#define W_APB 20544   // 2*64
#define W_ABIN 20672  // 2*10*8
#define W_AVEC 20832  // 2*8*8
#define W_AW 20960    // 2*64*64
#define W_AB 29152
#define W_RW 29280
#define W_RB 37472
#define W_END 37600
#define WCONV_BLOCKS 147  // ceil(W_END/256)

// ws byte offsets
#define O_FLAG 0
#define O_WBUF 256
#define O_ROWP 150784
#define O_CNTS 310784
#define O_TMP 470784
#define O_PART 634624
#define O_STB 635136
#define O_BIG 2635392  // stb + 64-int zero pad
#define XMP_BYTES 10240000ull   // R*64 u32
#define HR_BYTES 20480000ull    // R*64 float2
#define XM32_BYTES 20480000ull  // R*64 float2 (fallback)
#define NEED_LEAN (O_BIG + XMP_BYTES + HR_BYTES)  // 33,355,392 (< 43.6MB proven)
#define NEED_XM1 (O_BIG + XM32_BYTES)

static __device__ __forceinline__ float b2f(bf16 x) { return __bfloat162float(x); }
static __device__ __forceinline__ float ldv(const float* p, size_t i) { return p[i]; }
static __device__ __forceinline__ float ldv(const bf16* p, size_t i) { return __bfloat162float(p[i]); }
static __device__ __forceinline__ void stv(float* p, size_t i, float v) { p[i] = v; }
static __device__ __forceinline__ void stv(bf16* p, size_t i, float v) { p[i] = __float2bfloat16(v); }

// round-to-nearest-even f32 -> bf16 bits
static __device__ __forceinline__ unsigned int f2bb(float x) {
  union { float f; unsigned int u; } v;
  v.f = x;
  unsigned int r = v.u + 0x7FFFu + ((v.u >> 16) & 1u);
  return r >> 16;
}
static __device__ __forceinline__ unsigned int packxm(float xt, float mt) {
  return f2bb(xt) | (f2bb(mt) << 16);
}

// ---------------- detect + zero-init (fused) ----------------
// block 0: dtype flags; blocks 1..159: zero counts and stb pad.

__global__ void k_detect_init(const unsigned int* __restrict__ trip_w,
                              const unsigned short* __restrict__ emb_w, int* __restrict__ flag,
                              int* __restrict__ counts, int* __restrict__ stb) {
  int tid = threadIdx.x;
  if (blockIdx.x == 0) {
    if (tid < 64) {
      int lane = tid;
      unsigned int acc = 0;
      for (int i = lane; i < 1024; i += 64) acc |= trip_w[2 * i + 1];
      int votes = 0;
      for (int i = lane; i < 2048; i += 64) {
        unsigned short u = emb_w[2 * i];
        int ex = (u >> 7) & 0xFF;
        if (ex >= 90 && ex <= 130) votes++;
      }
      for (int off = 1; off < 64; off <<= 1) {
        acc |= __shfl_xor(acc, off);
        votes += __shfl_xor(votes, off);
      }
      if (lane == 0) {
        flag[0] = (acc == 0) ? 1 : 0;
        flag[1] = (votes < 1024) ? 1 : 0;
      }
    }
    return;
  }
  int g = (blockIdx.x - 1) * 256 + tid;
  for (int i = g; i < R_NUM; i += 159 * 256) counts[i] = 0;
  if (blockIdx.x == 1 && tid < 64) stb[E_NUM + tid] = 0;
}

// ---------------- hist + wconv (fused) ----------------

static __device__ __forceinline__ void load_edge(const unsigned int* __restrict__ w, int e,
                                                 int i64, int& h, int& t, int& b) {
  if (i64) {
    h = (int)w[6 * e + 0];
    t = (int)w[6 * e + 2];
    b = (int)w[6 * e + 4];
  } else {
    h = (int)w[3 * e + 0];
    t = (int)w[3 * e + 1];
    b = (int)w[3 * e + 2];
  }
}

__global__ void k_hist_wconv(const unsigned int* __restrict__ trip_w, const int* __restrict__ flag,
                             int* __restrict__ counts, const void* p1w, const void* p1b,
                             const void* apw, const void* apb, const void* abin, const void* avec,
                             const void* aw, const void* ab, const void* rw, const void* rb,
                             float* __restrict__ wbuf) {
  if (blockIdx.x < WCONV_BLOCKS) {
    int i = blockIdx.x * 256 + threadIdx.x;
    if (i >= W_END) return;
    const void* src;
    int off;
    if (i < W_P1B) { src = p1w; off = i - W_P1W; }
    else if (i < W_APW) { src = p1b; off = i - W_P1B; }
    else if (i < W_APB) { src = apw; off = i - W_APW; }
    else if (i < W_ABIN) { src = apb; off = i - W_APB; }
    else if (i < W_AVEC) { src = abin; off = i - W_ABIN; }
    else if (i < W_AW) { src = avec; off = i - W_AVEC; }
    else if (i < W_AB) { src = aw; off = i - W_AW; }
    else if (i < W_RW) { src = ab; off = i - W_AB; }
    else if (i < W_RB) { src = rw; off = i - W_RW; }
    else { src = rb; off = i - W_RB; }
    wbuf[i] = flag[1] ? ((const float*)src)[off] : b2f(((const bf16*)src)[off]);
    return;
  }
  int e = (blockIdx.x - WCONV_BLOCKS) * 256 + threadIdx.x;
  if (e >= E_NUM) return;
  int h, t, b;
  load_edge(trip_w, e, flag[0], h, t, b);
  atomicAdd(&counts[h], 1);
}

// ---------------- scan (2 kernels) ----------------

__global__ void k_scan_a(const int* __restrict__ counts, int* __restrict__ tmp,
                         int* __restrict__ partial) {
  __shared__ int sd[1024];
  int tid = threadIdx.x;
  int idx = blockIdx.x * 1024 + tid;
  int v = (idx < R_NUM) ? counts[idx] : 0;
  sd[tid] = v;
  __syncthreads();
  for (int off = 1; off < 1024; off <<= 1) {
    int t = (tid >= off) ? sd[tid - off] : 0;
    __syncthreads();
    sd[tid] += t;
    __syncthreads();
  }
  if (idx < R_NUM) tmp[idx] = sd[tid];
  if (tid == 1023) partial[blockIdx.x] = sd[1023];
}

__global__ void k_scan_c(const int* __restrict__ counts, const int* __restrict__ tmp,
                         const int* __restrict__ partial, int* __restrict__ row_ptr) {
  __shared__ int soff;
  if (threadIdx.x < 64) {
    int lane = threadIdx.x;
    int p = (lane < (int)blockIdx.x) ? partial[lane] : 0;  // gridDim 40 <= 64
    for (int d = 1; d < 64; d <<= 1) p += __shfl_xor(p, d);
    if (lane == 0) soff = p;
  }
  __syncthreads();
  int idx = blockIdx.x * 1024 + threadIdx.x;
  if (idx < R_NUM) row_ptr[idx] = tmp[idx] - counts[idx] + soff;
}

// scatter bumps row_ptr: afterwards row_ptr[r] == end(r); beg(r) = r ? row_ptr[r-1] : 0
__global__ void k_scatter(const unsigned int* __restrict__ trip_w, const int* __restrict__ flag,
                          int* __restrict__ row_ptr, int* __restrict__ stb) {
  int e = blockIdx.x * 256 + threadIdx.x;
  if (e >= E_NUM) return;
  int h, t, b;
  load_edge(trip_w, e, flag[0], h, t, b);
  int pos = atomicAdd(&row_ptr[h], 1);
  stb[pos] = (t & 0xFFFF) | (b << 16);
}

// ---------------- fused emb0 + packed XM(l0) + HR(l0); 8 rows/thread ----------------

__global__ void __launch_bounds__(256, 4) k_emb0xm_p(const void* __restrict__ A,
                                                     const int* __restrict__ flag,
                                                     const float* __restrict__ wbuf,
                                                     float* __restrict__ emb,
                                                     unsigned int* __restrict__ XMp,
                                                     float2* __restrict__ HR) {
  int j = threadIdx.x & 63;
  int g = threadIdx.x >> 6;
  int r0 = blockIdx.x * 32 + g * 8;
  int f32 = flag[1];
  __shared__ float sA[32][64];
  for (int k = threadIdx.x; k < 2048; k += 256) {
    int rr = k >> 6, cc = k & 63;
    size_t idx = (size_t)(blockIdx.x * 32 + rr) * 64 + cc;
    sA[rr][cc] = f32 ? ((const float*)A)[idx] : b2f(((const bf16*)A)[idx]);
  }
  __syncthreads();
  int base = g * 8;
  float a[8] = {0.f, 0.f, 0.f, 0.f, 0.f, 0.f, 0.f, 0.f};
  {
    const float* W = wbuf + W_P1W;
    for (int i = 0; i < 64; i++) {
      float w = W[i * 64 + j];
#pragma unroll
      for (int n = 0; n < 8; n++) a[n] = fmaf(sA[base + n][i], w, a[n]);
    }
    float bj = wbuf[W_P1B + j];
#pragma unroll
    for (int n = 0; n < 8; n++) {
      a[n] = fmaxf(a[n] + bj, 0.f);
      emb[(size_t)(r0 + n) * 64 + j] = a[n];
    }
  }
  __syncthreads();
#pragma unroll
  for (int n = 0; n < 8; n++) sA[base + n][j] = a[n];
  __syncthreads();
  {
    const float* pwb = wbuf + W_APW + 4096;  // layer-0 bottom proj
    const float* aw = wbuf + W_AW;
    float axt[8] = {0.f, 0.f, 0.f, 0.f, 0.f, 0.f, 0.f, 0.f};
    float amt[8] = {0.f, 0.f, 0.f, 0.f, 0.f, 0.f, 0.f, 0.f};
    for (int i = 0; i < 64; i++) {
      float wt = pwb[i * 64 + j];
      float wm = aw[i * 64 + j];
#pragma unroll
      for (int n = 0; n < 8; n++) {
        float e = sA[base + n][i];
        axt[n] = fmaf(e, wt, axt[n]);
        amt[n] = fmaf(e, wm, amt[n]);
      }
    }
    float abj = wbuf[W_AB + j];
#pragma unroll
    for (int n = 0; n < 8; n++)
      XMp[(size_t)(r0 + n) * 64 + j] = packxm(axt[n], amt[n] + abj);
  }
  {
    const float* pwt = wbuf + W_APW;  // layer-0 top proj
    const float* rw = wbuf + W_RW;
    float axh[8] = {0.f, 0.f, 0.f, 0.f, 0.f, 0.f, 0.f, 0.f};
    float ars[8] = {0.f, 0.f, 0.f, 0.f, 0.f, 0.f, 0.f, 0.f};
    for (int i = 0; i < 64; i++) {
      float wh = pwt[i * 64 + j];
      float wr = rw[i * 64 + j];
#pragma unroll
      for (int n = 0; n < 8; n++) {
        float e = sA[base + n][i];
        axh[n] = fmaf(e, wh, axh[n]);
        ars[n] = fmaf(e, wr, ars[n]);
      }
    }
    float pbj = wbuf[W_APB + j];
    float rbj = wbuf[W_RB + j];
#pragma unroll
    for (int n = 0; n < 8; n++)
      HR[(size_t)(r0 + n) * 64 + j] = make_float2(axh[n] + pbj, fmaxf(ars[n] + rbj, 0.f));
  }
}

// ---------------- node-parallel packed XM+HR, layer l; 8 rows/thread ----------------

__global__ void __launch_bounds__(256, 4) k_xmhr_p(const float* __restrict__ emb,
                                                   const float* __restrict__ wbuf, int l,
                                                   unsigned int* __restrict__ XMp,
                                                   float2* __restrict__ HR) {
  int j = threadIdx.x & 63;
  int g = threadIdx.x >> 6;
  int r0 = blockIdx.x * 32 + g * 8;
  __shared__ float sE[32][64];
  for (int k = threadIdx.x; k < 2048; k += 256) {
    int rr = k >> 6, cc = k & 63;
    sE[rr][cc] = emb[(size_t)(blockIdx.x * 32 + rr) * 64 + cc];
  }
  __syncthreads();
  int base = g * 8;
  {
    const float* pwb = wbuf + W_APW + l * 8192 + 4096;
    const float* aw = wbuf + W_AW + l * 4096;
    float axt[8] = {0.f, 0.f, 0.f, 0.f, 0.f, 0.f, 0.f, 0.f};
    float amt[8] = {0.f, 0.f, 0.f, 0.f, 0.f, 0.f, 0.f, 0.f};
    for (int i = 0; i < 64; i++) {
      float wt = pwb[i * 64 + j];
      float wm = aw[i * 64 + j];
#pragma unroll
      for (int n = 0; n < 8; n++) {
        float e = sE[base + n][i];
        axt[n] = fmaf(e, wt, axt[n]);
        amt[n] = fmaf(e, wm, amt[n]);
      }
    }
    float abj = wbuf[W_AB + l * 64 + j];
#pragma unroll
    for (int n = 0; n < 8; n++)
      XMp[(size_t)(r0 + n) * 64 + j] = packxm(axt[n], amt[n] + abj);
  }
  {
    const float* pwt = wbuf + W_APW + l * 8192;
    const float* rw = wbuf + W_RW + l * 4096;
    float axh[8] = {0.f, 0.f, 0.f, 0.f, 0.f, 0.f, 0.f, 0.f};
    float ars[8] = {0.f, 0.f, 0.f, 0.f, 0.f, 0.f, 0.f, 0.f};
    for (int i = 0; i < 64; i++) {
      float wh = pwt[i * 64 + j];
      float wr = rw[i * 64 + j];
#pragma unroll
      for (int n = 0; n < 8; n++) {
        float e = sE[base + n][i];
        axh[n] = fmaf(e, wh, axh[n]);
        ars[n] = fmaf(e, wr, ars[n]);
      }
    }
    float pbj = wbuf[W_APB + l * 64 + j];
    float rbj = wbuf[W_RB + l * 64 + j];
#pragma unroll
    for (int n = 0; n < 8; n++)
      HR[(size_t)(r0 + n) * 64 + j] = make_float2(axh[n] + pbj, fmaxf(ars[n] + rbj, 0.f));
  }
}

// ---------------- lean edge kernel: packed-bf16 XM gathers, window-16 ----------------

__global__ void __launch_bounds__(256, 4) k_edge_lean(
    const int* __restrict__ row_ptr, const int* __restrict__ stb,
    const unsigned int* __restrict__ XMp, const float2* __restrict__ HR,
    const float* __restrict__ wbuf, int l, float* __restrict__ emb) {
  __shared__ float sab[80];
  int tid = threadIdx.x;
  int lane = tid & 63;
  int w = tid >> 6;
  int hh = lane >> 3;
  if (tid < 80) {
    float a = wbuf[W_ABIN + l * 80 + tid];
    sab[tid] = (a > 0.f) ? a : 0.2f * a;
  }
  __syncthreads();
  float av = wbuf[W_AVEC + l * 64 + lane];

  int r = blockIdx.x * 4 + w;
  float2 hr = HR[(size_t)r * 64 + lane];
  int beg = (r == 0) ? 0 : row_ptr[r - 1];
  int end = row_ptr[r];
  beg = __builtin_amdgcn_readfirstlane(beg);
  end = __builtin_amdgcn_readfirstlane(end);

  float xh = hr.x;
  float num = 0.f, den = 0.f;
  for (int j = beg; j < end; j += 16) {
    int pk[16];
    unsigned int xp[16];
#pragma unroll
    for (int k = 0; k < 16; k++) pk[k] = stb[j + k];  // scalar loads
#pragma unroll
    for (int k = 0; k < 16; k++)
      xp[k] = XMp[(size_t)(pk[k] & 0xFFFF) * 64 + lane];  // 16 gathers in flight
#pragma unroll
    for (int k = 0; k < 16; k++) {
      float xt = __uint_as_float(xp[k] << 16);
      float mt = __uint_as_float(xp[k] & 0xFFFF0000u);
      float z = xh + xt;
      z = (z > 0.f) ? z : 0.2f * z;
      float v = z * av;
      v += __shfl_xor(v, 1);
      v += __shfl_xor(v, 2);
      v += __shfl_xor(v, 4);
      float e = __expf(v + sab[(pk[k] >> 16) * 8 + hh]);
      e = (j + k < end) ? e : 0.f;
      den += e;
      num = fmaf(mt, e, num);
    }
  }
  emb[(size_t)r * 64 + lane] = fmaxf(num / (den + 1e-16f), 0.f) + hr.y;
}

// ---------------- XM1 fallback kernels (f32 XM, in-kernel preamble) ----------------

__global__ void k_emb0(const void* __restrict__ A, const int* __restrict__ flag,
                       const float* __restrict__ wbuf, float* __restrict__ emb) {
  int j = threadIdx.x & 63;
  int g = threadIdx.x >> 6;
  int r0 = blockIdx.x * 16 + g * 4;
  int f32 = flag[1];
  __shared__ float sA[16][64];
  for (int k = threadIdx.x; k < 1024; k += 256) {
    int rr = k >> 6, cc = k & 63;
    size_t idx = (size_t)(blockIdx.x * 16 + rr) * 64 + cc;
    sA[rr][cc] = f32 ? ((const float*)A)[idx] : b2f(((const bf16*)A)[idx]);
  }
  __syncthreads();
  const float* W = wbuf + W_P1W;
  float a[4] = {0.f, 0.f, 0.f, 0.f};
  int base = g * 4;
  for (int i = 0; i < 64; i++) {
    float w = W[i * 64 + j];
#pragma unroll
    for (int n = 0; n < 4; n++) a[n] = fmaf(sA[base + n][i], w, a[n]);
  }
  float bj = wbuf[W_P1B + j];
#pragma unroll
  for (int n = 0; n < 4; n++)
    emb[(size_t)(r0 + n) * 64 + j] = fmaxf(a[n] + bj, 0.f);
}

__global__ void k_xm(const float* __restrict__ emb, const float* __restrict__ wbuf, int l,
                     float2* __restrict__ XM) {
  int j = threadIdx.x & 63;
  int g = threadIdx.x >> 6;
  int r0 = blockIdx.x * 16 + g * 4;
  __shared__ float sE[16][64];
  for (int k = threadIdx.x; k < 1024; k += 256) {
    int rr = k >> 6, cc = k & 63;
    sE[rr][cc] = emb[(size_t)(blockIdx.x * 16 + rr) * 64 + cc];
  }
  __syncthreads();
  const float* pwb = wbuf + W_APW + l * 8192 + 4096;
  const float* aw = wbuf + W_AW + l * 4096;
  float axt[4] = {0.f, 0.f, 0.f, 0.f};
  float amt[4] = {0.f, 0.f, 0.f, 0.f};
  int base = g * 4;
  for (int i = 0; i < 64; i++) {
    float wt = pwb[i * 64 + j];
    float wm = aw[i * 64 + j];
#pragma unroll
    for (int n = 0; n < 4; n++) {
      float e = sE[base + n][i];
      axt[n] = fmaf(e, wt, axt[n]);
      amt[n] = fmaf(e, wm, amt[n]);
    }
  }
  float abj = wbuf[W_AB + l * 64 + j];
#pragma unroll
  for (int n = 0; n < 4; n++)
    XM[(size_t)(r0 + n) * 64 + j] = make_float2(axt[n], amt[n] + abj);
}

__global__ void __launch_bounds__(256, 4) k_edge_f(
    const int* __restrict__ row_ptr, const int* __restrict__ stb, const float2* __restrict__ XM,
    const float* __restrict__ wbuf, int l, float* __restrict__ emb) {
  __shared__ float sab[80];
  int tid = threadIdx.x;
  int lane = tid & 63;
  int w = tid >> 6;
  int hh = lane >> 3;
  if (tid < 80) {
    float a = wbuf[W_ABIN + l * 80 + tid];
    sab[tid] = (a > 0.f) ? a : 0.2f * a;
  }
  __syncthreads();

  const float* pwt = wbuf + W_APW + l * 8192;
  const float* rwp = wbuf + W_RW + l * 4096;
  float av = wbuf[W_AVEC + l * 64 + lane];
  float xh0 = wbuf[W_APB + l * 64 + lane];
  float res0 = wbuf[W_RB + l * 64 + lane];

  int r0 = blockIdx.x * 16 + w * 4;
  for (int rr = 0; rr < 4; rr++) {
    int r = r0 + rr;
    float ev = emb[(size_t)r * 64 + lane];
    float xh = xh0, res = res0;
#pragma unroll 16
    for (int i = 0; i < 64; i++) {
      float e = __shfl(ev, i);
      xh = fmaf(e, pwt[i * 64 + lane], xh);
      res = fmaf(e, rwp[i * 64 + lane], res);
    }
    res = fmaxf(res, 0.f);

    int beg = (r == 0) ? 0 : row_ptr[r - 1];
    int end = row_ptr[r];
    beg = __builtin_amdgcn_readfirstlane(beg);
    end = __builtin_amdgcn_readfirstlane(end);

    float num = 0.f, den = 0.f;
    for (int j = beg; j < end; j += 16) {
      int pk[16];
      float2 xmv[16];
#pragma unroll
      for (int k = 0; k < 16; k++) pk[k] = stb[j + k];
#pragma unroll
      for (int k = 0; k < 16; k++) xmv[k] = XM[(size_t)(pk[k] & 0xFFFF) * 64 + lane];
#pragma unroll
      for (int k = 0; k < 16; k++) {
        float z = xh + xmv[k].x;
        z = (z > 0.f) ? z : 0.2f * z;
        float v = z * av;
        v += __shfl_xor(v, 1);
        v += __shfl_xor(v, 2);
        v += __shfl_xor(v, 4);
        float e = __expf(v + sab[(pk[k] >> 16) * 8 + hh]);
        e = (j + k < end) ? e : 0.f;
        den += e;
        num = fmaf(xmv[k].y, e, num);
      }
    }
    emb[(size_t)r * 64 + lane] = fmaxf(num / (den + 1e-16f), 0.f) + res;
  }
}

// ---------------- Plan D fallback (tiny ws): per-edge recompute ----------------

static __device__ __forceinline__ float dotcol(const float* __restrict__ Wm, float val, int lane) {
  float acc = 0.f;
  for (int i = 0; i < 64; i++) acc = fmaf(__shfl(val, i), Wm[i * 64 + lane], acc);
  return acc;
}

template <typename TIN, typename TOUT>
__global__ void k_edge_d(const int* __restrict__ row_ptr, const int* __restrict__ stb,
                         const float* __restrict__ wbuf, int l, const TIN* __restrict__ emb_in,
                         TOUT* __restrict__ emb_out) {
  __shared__ float sab[80];
  int tid = threadIdx.x;
  int lane = tid & 63;
  int w = tid >> 6;
  int r = blockIdx.x * 4 + w;
  int hh = lane >> 3;
  if (tid < 80) {
    float a = wbuf[W_ABIN + l * 80 + tid];
    sab[tid] = (a > 0.f) ? a : 0.2f * a;
  }
  __syncthreads();
  const float* pwt = wbuf + W_APW + l * 8192;
  const float* pwb = pwt + 4096;
  const float* aw = wbuf + W_AW + l * 4096;
  const float* rw = wbuf + W_RW + l * 4096;

  float ev = ldv(emb_in, (size_t)r * 64 + lane);
  float xh = wbuf[W_APB + l * 64 + lane];
  float res = wbuf[W_RB + l * 64 + lane];
  for (int i = 0; i < 64; i++) {
    float e = __shfl(ev, i);
    xh = fmaf(e, pwt[i * 64 + lane], xh);
    res = fmaf(e, rw[i * 64 + lane], res);
  }
  res = fmaxf(res, 0.f);
  float av = wbuf[W_AVEC + l * 64 + lane];
  float abl = wbuf[W_AB + l * 64 + lane];

  int beg = (r == 0) ? 0 : row_ptr[r - 1];
  int end = row_ptr[r];
  float num = 0.f, den = 0.f;
  for (int j = beg; j < end; j++) {
    int p = stb[j];
    int t = p & 0xFFFF;
    float tv = ldv(emb_in, (size_t)t * 64 + lane);
    float z = xh + dotcol(pwb, tv, lane);
    z = (z > 0.f) ? z : 0.2f * z;
    float v = z * av;
    v += __shfl_xor(v, 1);
    v += __shfl_xor(v, 2);
    v += __shfl_xor(v, 4);
    float e = __expf(v + sab[(p >> 16) * 8 + hh]);
    den += e;
    float mt = dotcol(aw, tv, lane) + abl;
    num = fmaf(mt, e, num);
  }
  stv(emb_out, (size_t)r * 64 + lane, fmaxf(num / (den + 1e-16f), 0.f) + res);
}

// ---------------- launch ----------------

extern "C" void kernel_launch(void* const* d_in, const int* in_sizes, int n_in,
                              void* d_out, int out_size, void* d_ws, size_t ws_size,
                              hipStream_t stream) {
  const unsigned int* trip_w = (const unsigned int*)d_in[0];
  const void* rel_emb = d_in[1];
  float* emb = (float*)d_out;

  char* ws = (char*)d_ws;
  int* flag = (int*)(ws + O_FLAG);
  float* wbuf = (float*)(ws + O_WBUF);
  int* row_ptr = (int*)(ws + O_ROWP);
  int* counts = (int*)(ws + O_CNTS);
  int* tmp = (int*)(ws + O_TMP);
  int* partial = (int*)(ws + O_PART);
  int* stb = (int*)(ws + O_STB);
  char* big = ws + O_BIG;

  k_detect_init<<<160, 256, 0, stream>>>(trip_w, (const unsigned short*)rel_emb, flag, counts,
                                         stb);
  int eb_blocks = (E_NUM + 255) / 256;
  k_hist_wconv<<<WCONV_BLOCKS + eb_blocks, 256, 0, stream>>>(
      trip_w, flag, counts, d_in[2], d_in[3], d_in[4], d_in[5], d_in[6], d_in[7], d_in[8],
      d_in[9], d_in[10], d_in[11], wbuf);
  k_scan_a<<<40, 1024, 0, stream>>>(counts, tmp, partial);
  k_scan_c<<<40, 1024, 0, stream>>>(counts, tmp, partial, row_ptr);
  k_scatter<<<eb_blocks, 256, 0, stream>>>(trip_w, flag, row_ptr, stb);

  if (ws_size >= NEED_LEAN) {
    unsigned int* XMp = (unsigned int*)big;
    float2* HR = (float2*)(big + XMP_BYTES);
    k_emb0xm_p<<<R_NUM / 32, 256, 0, stream>>>(rel_emb, flag, wbuf, emb, XMp, HR);
    k_edge_lean<<<R_NUM / 4, 256, 0, stream>>>(row_ptr, stb, XMp, HR, wbuf, 0, emb);
    k_xmhr_p<<<R_NUM / 32, 256, 0, stream>>>(emb, wbuf, 1, XMp, HR);
    k_edge_lean<<<R_NUM / 4, 256, 0, stream>>>(row_ptr, stb, XMp, HR, wbuf, 1, emb);
  } else if (ws_size >= NEED_XM1) {
    float2* XM = (float2*)big;
    k_emb0<<<R_NUM / 16, 256, 0, stream>>>(rel_emb, flag, wbuf, emb);
    k_xm<<<R_NUM / 16, 256, 0, stream>>>(emb, wbuf, 0, XM);
    k_edge_f<<<R_NUM / 16, 256, 0, stream>>>(row_ptr, stb, XM, wbuf, 0, emb);
    k_xm<<<R_NUM / 16, 256, 0, stream>>>(emb, wbuf, 1, XM);
    k_edge_f<<<R_NUM / 16, 256, 0, stream>>>(row_ptr, stb, XM, wbuf, 1, emb);
  } else {
    k_emb0<<<R_NUM / 16, 256, 0, stream>>>(rel_emb, flag, wbuf, emb);
    bf16* embB = (bf16*)big;
    k_edge_d<float, bf16><<<R_NUM / 4, 256, 0, stream>>>(row_ptr, stb, wbuf, 0, emb, embB);
    k_edge_d<bf16, float><<<R_NUM / 4, 256, 0, stream>>>(row_ptr, stb, wbuf, 1, embB, emb);
  }
}

// Round 12
// 259.705 us; speedup vs baseline: 1.8825x; 1.0599x over previous
//
#include <hip/hip_runtime.h>
#include <hip/hip_bf16.h>

typedef __hip_bfloat16 bf16;

#define R_NUM 40000
#define E_NUM 500000

// wbuf layout (f32 element offsets)
#define W_P1W 0
#define W_P1B 4096
#define W_APW 4160    // 2*128*64
#define W_APB 20544   // 2*64
#define W_ABIN 20672  // 2*10*8
#define W_AVEC 20832  // 2*8*8
#define W_AW 20960    // 2*64*64
#define W_AB 29152
#define W_RW 29280
#define W_RB 37472
#define W_END 37600
#define WCONV_BLOCKS 147  // ceil(W_END/256)

// ws byte offsets
#define O_FLAG 0
#define O_WBUF 256
#define O_ROWP 150784
#define O_CNTS 310784
#define O_TMP 470784
#define O_PART 634624
#define O_STB 635136
#define O_BIG 2635392  // stb + 64-int zero pad
#define XMP_BYTES 10240000ull   // R*64 u32
#define HR_BYTES 20480000ull    // R*64 float2
#define XM32_BYTES 20480000ull  // R*64 float2 (fallback)
#define NEED_LEAN (O_BIG + XMP_BYTES + HR_BYTES)  // 33,355,392 (fits; ws ~268 MB observed)
#define NEED_XM1 (O_BIG + XM32_BYTES)

static __device__ __forceinline__ float b2f(bf16 x) { return __bfloat162float(x); }
static __device__ __forceinline__ float ldv(const float* p, size_t i) { return p[i]; }
static __device__ __forceinline__ float ldv(const bf16* p, size_t i) { return __bfloat162float(p[i]); }
static __device__ __forceinline__ void stv(float* p, size_t i, float v) { p[i] = v; }
static __device__ __forceinline__ void stv(bf16* p, size_t i, float v) { p[i] = __float2bfloat16(v); }

// round-to-nearest-even f32 -> bf16 bits
static __device__ __forceinline__ unsigned int f2bb(float x) {
  union { float f; unsigned int u; } v;
  v.f = x;
  unsigned int r = v.u + 0x7FFFu + ((v.u >> 16) & 1u);
  return r >> 16;
}
static __device__ __forceinline__ unsigned int packxm(float xt, float mt) {
  return f2bb(xt) | (f2bb(mt) << 16);
}

// ---------------- detect + zero-init (fused) ----------------

__global__ void k_detect_init(const unsigned int* __restrict__ trip_w,
                              const unsigned short* __restrict__ emb_w, int* __restrict__ flag,
                              int* __restrict__ counts, int* __restrict__ stb) {
  int tid = threadIdx.x;
  if (blockIdx.x == 0) {
    if (tid < 64) {
      int lane = tid;
      unsigned int acc = 0;
      for (int i = lane; i < 1024; i += 64) acc |= trip_w[2 * i + 1];
      int votes = 0;
      for (int i = lane; i < 2048; i += 64) {
        unsigned short u = emb_w[2 * i];
        int ex = (u >> 7) & 0xFF;
        if (ex >= 90 && ex <= 130) votes++;
      }
      for (int off = 1; off < 64; off <<= 1) {
        acc |= __shfl_xor(acc, off);
        votes += __shfl_xor(votes, off);
      }
      if (lane == 0) {
        flag[0] = (acc == 0) ? 1 : 0;
        flag[1] = (votes < 1024) ? 1 : 0;
      }
    }
    return;
  }
  int g = (blockIdx.x - 1) * 256 + tid;
  for (int i = g; i < R_NUM; i += 159 * 256) counts[i] = 0;
  if (blockIdx.x == 1 && tid < 64) stb[E_NUM + tid] = 0;
}

// ---------------- hist + wconv (fused) ----------------

static __device__ __forceinline__ void load_edge(const unsigned int* __restrict__ w, int e,
                                                 int i64, int& h, int& t, int& b) {
  if (i64) {
    h = (int)w[6 * e + 0];
    t = (int)w[6 * e + 2];
    b = (int)w[6 * e + 4];
  } else {
    h = (int)w[3 * e + 0];
    t = (int)w[3 * e + 1];
    b = (int)w[3 * e + 2];
  }
}

__global__ void k_hist_wconv(const unsigned int* __restrict__ trip_w, const int* __restrict__ flag,
                             int* __restrict__ counts, const void* p1w, const void* p1b,
                             const void* apw, const void* apb, const void* abin, const void* avec,
                             const void* aw, const void* ab, const void* rw, const void* rb,
                             float* __restrict__ wbuf) {
  if (blockIdx.x < WCONV_BLOCKS) {
    int i = blockIdx.x * 256 + threadIdx.x;
    if (i >= W_END) return;
    const void* src;
    int off;
    if (i < W_P1B) { src = p1w; off = i - W_P1W; }
    else if (i < W_APW) { src = p1b; off = i - W_P1B; }
    else if (i < W_APB) { src = apw; off = i - W_APW; }
    else if (i < W_ABIN) { src = apb; off = i - W_APB; }
    else if (i < W_AVEC) { src = abin; off = i - W_ABIN; }
    else if (i < W_AW) { src = avec; off = i - W_AVEC; }
    else if (i < W_AB) { src = aw; off = i - W_AW; }
    else if (i < W_RW) { src = ab; off = i - W_AB; }
    else if (i < W_RB) { src = rw; off = i - W_RW; }
    else { src = rb; off = i - W_RB; }
    wbuf[i] = flag[1] ? ((const float*)src)[off] : b2f(((const bf16*)src)[off]);
    return;
  }
  int e = (blockIdx.x - WCONV_BLOCKS) * 256 + threadIdx.x;
  if (e >= E_NUM) return;
  int h, t, b;
  load_edge(trip_w, e, flag[0], h, t, b);
  atomicAdd(&counts[h], 1);
}

// ---------------- scan (2 kernels) ----------------

__global__ void k_scan_a(const int* __restrict__ counts, int* __restrict__ tmp,
                         int* __restrict__ partial) {
  __shared__ int sd[1024];
  int tid = threadIdx.x;
  int idx = blockIdx.x * 1024 + tid;
  int v = (idx < R_NUM) ? counts[idx] : 0;
  sd[tid] = v;
  __syncthreads();
  for (int off = 1; off < 1024; off <<= 1) {
    int t = (tid >= off) ? sd[tid - off] : 0;
    __syncthreads();
    sd[tid] += t;
    __syncthreads();
  }
  if (idx < R_NUM) tmp[idx] = sd[tid];
  if (tid == 1023) partial[blockIdx.x] = sd[1023];
}

__global__ void k_scan_c(const int* __restrict__ counts, const int* __restrict__ tmp,
                         const int* __restrict__ partial, int* __restrict__ row_ptr) {
  __shared__ int soff;
  if (threadIdx.x < 64) {
    int lane = threadIdx.x;
    int p = (lane < (int)blockIdx.x) ? partial[lane] : 0;  // gridDim 40 <= 64
    for (int d = 1; d < 64; d <<= 1) p += __shfl_xor(p, d);
    if (lane == 0) soff = p;
  }
  __syncthreads();
  int idx = blockIdx.x * 1024 + threadIdx.x;
  if (idx < R_NUM) row_ptr[idx] = tmp[idx] - counts[idx] + soff;
}

// scatter bumps row_ptr: afterwards row_ptr[r] == end(r); beg(r) = r ? row_ptr[r-1] : 0
__global__ void k_scatter(const unsigned int* __restrict__ trip_w, const int* __restrict__ flag,
                          int* __restrict__ row_ptr, int* __restrict__ stb) {
  int e = blockIdx.x * 256 + threadIdx.x;
  if (e >= E_NUM) return;
  int h, t, b;
  load_edge(trip_w, e, flag[0], h, t, b);
  int pos = atomicAdd(&row_ptr[h], 1);
  stb[pos] = (t & 0xFFFF) | (b << 16);
}

// ---------------- fused emb0 + packed XM(l0) + HR(l0); 8 rows/thread ----------------
// Phase 1: emb0 (one weight stream). Phase 2: 4 fused streams sharing one set of
// float4 LDS reads (ds_read_b128) -- DS-instruction diet (R11: transforms were
// LDS-issue-bound at ~5.8cyc per ds_read_b32 broadcast).

__global__ void __launch_bounds__(256, 4) k_emb0xm_p(const void* __restrict__ A,
                                                     const int* __restrict__ flag,
                                                     const float* __restrict__ wbuf,
                                                     float* __restrict__ emb,
                                                     unsigned int* __restrict__ XMp,
                                                     float2* __restrict__ HR) {
  int j = threadIdx.x & 63;
  int g = threadIdx.x >> 6;
  int r0 = blockIdx.x * 32 + g * 8;
  int f32 = flag[1];
  __shared__ float sA[32][64];
  for (int k = threadIdx.x; k < 2048; k += 256) {
    int rr = k >> 6, cc = k & 63;
    size_t idx = (size_t)(blockIdx.x * 32 + rr) * 64 + cc;
    sA[rr][cc] = f32 ? ((const float*)A)[idx] : b2f(((const bf16*)A)[idx]);
  }
  __syncthreads();
  int base = g * 8;
  float a[8] = {0.f, 0.f, 0.f, 0.f, 0.f, 0.f, 0.f, 0.f};
  {
    const float* W = wbuf + W_P1W;
    for (int i4 = 0; i4 < 64; i4 += 4) {
      float4 ev[8];
#pragma unroll
      for (int n = 0; n < 8; n++) ev[n] = *(const float4*)&sA[base + n][i4];
#pragma unroll
      for (int di = 0; di < 4; di++) {
        float w = W[(i4 + di) * 64 + j];
#pragma unroll
        for (int n = 0; n < 8; n++)
          a[n] = fmaf(((const float*)&ev[n])[di], w, a[n]);
      }
    }
    float bj = wbuf[W_P1B + j];
#pragma unroll
    for (int n = 0; n < 8; n++) {
      a[n] = fmaxf(a[n] + bj, 0.f);
      emb[(size_t)(r0 + n) * 64 + j] = a[n];
    }
  }
  __syncthreads();
#pragma unroll
  for (int n = 0; n < 8; n++) sA[base + n][j] = a[n];
  __syncthreads();
  {
    const float* pwb = wbuf + W_APW + 4096;  // layer-0 bottom proj
    const float* aw = wbuf + W_AW;
    const float* pwt = wbuf + W_APW;  // layer-0 top proj
    const float* rw = wbuf + W_RW;
    float axt[8] = {0.f, 0.f, 0.f, 0.f, 0.f, 0.f, 0.f, 0.f};
    float amt[8] = {0.f, 0.f, 0.f, 0.f, 0.f, 0.f, 0.f, 0.f};
    float axh[8] = {0.f, 0.f, 0.f, 0.f, 0.f, 0.f, 0.f, 0.f};
    float ars[8] = {0.f, 0.f, 0.f, 0.f, 0.f, 0.f, 0.f, 0.f};
    for (int i4 = 0; i4 < 64; i4 += 4) {
      float4 ev[8];
#pragma unroll
      for (int n = 0; n < 8; n++) ev[n] = *(const float4*)&sA[base + n][i4];
#pragma unroll
      for (int di = 0; di < 4; di++) {
        int i = i4 + di;
        float wt = pwb[i * 64 + j];
        float wm = aw[i * 64 + j];
        float wh = pwt[i * 64 + j];
        float wr = rw[i * 64 + j];
#pragma unroll
        for (int n = 0; n < 8; n++) {
          float e = ((const float*)&ev[n])[di];
          axt[n] = fmaf(e, wt, axt[n]);
          amt[n] = fmaf(e, wm, amt[n]);
          axh[n] = fmaf(e, wh, axh[n]);
          ars[n] = fmaf(e, wr, ars[n]);
        }
      }
    }
    float abj = wbuf[W_AB + j];
    float pbj = wbuf[W_APB + j];
    float rbj = wbuf[W_RB + j];
#pragma unroll
    for (int n = 0; n < 8; n++) {
      XMp[(size_t)(r0 + n) * 64 + j] = packxm(axt[n], amt[n] + abj);
      HR[(size_t)(r0 + n) * 64 + j] = make_float2(axh[n] + pbj, fmaxf(ars[n] + rbj, 0.f));
    }
  }
}

// ---------------- node-parallel packed XM+HR, layer l; 4 fused streams ----------------

__global__ void __launch_bounds__(256, 4) k_xmhr_p(const float* __restrict__ emb,
                                                   const float* __restrict__ wbuf, int l,
                                                   unsigned int* __restrict__ XMp,
                                                   float2* __restrict__ HR) {
  int j = threadIdx.x & 63;
  int g = threadIdx.x >> 6;
  int r0 = blockIdx.x * 32 + g * 8;
  __shared__ float sE[32][64];
  for (int k = threadIdx.x; k < 2048; k += 256) {
    int rr = k >> 6, cc = k & 63;
    sE[rr][cc] = emb[(size_t)(blockIdx.x * 32 + rr) * 64 + cc];
  }
  __syncthreads();
  int base = g * 8;
  const float* pwb = wbuf + W_APW + l * 8192 + 4096;
  const float* aw = wbuf + W_AW + l * 4096;
  const float* pwt = wbuf + W_APW + l * 8192;
  const float* rw = wbuf + W_RW + l * 4096;
  float axt[8] = {0.f, 0.f, 0.f, 0.f, 0.f, 0.f, 0.f, 0.f};
  float amt[8] = {0.f, 0.f, 0.f, 0.f, 0.f, 0.f, 0.f, 0.f};
  float axh[8] = {0.f, 0.f, 0.f, 0.f, 0.f, 0.f, 0.f, 0.f};
  float ars[8] = {0.f, 0.f, 0.f, 0.f, 0.f, 0.f, 0.f, 0.f};
  for (int i4 = 0; i4 < 64; i4 += 4) {
    float4 ev[8];
#pragma unroll
    for (int n = 0; n < 8; n++) ev[n] = *(const float4*)&sE[base + n][i4];
#pragma unroll
    for (int di = 0; di < 4; di++) {
      int i = i4 + di;
      float wt = pwb[i * 64 + j];
      float wm = aw[i * 64 + j];
      float wh = pwt[i * 64 + j];
      float wr = rw[i * 64 + j];
#pragma unroll
      for (int n = 0; n < 8; n++) {
        float e = ((const float*)&ev[n])[di];
        axt[n] = fmaf(e, wt, axt[n]);
        amt[n] = fmaf(e, wm, amt[n]);
        axh[n] = fmaf(e, wh, axh[n]);
        ars[n] = fmaf(e, wr, ars[n]);
      }
    }
  }
  float abj = wbuf[W_AB + l * 64 + j];
  float pbj = wbuf[W_APB + l * 64 + j];
  float rbj = wbuf[W_RB + l * 64 + j];
#pragma unroll
  for (int n = 0; n < 8; n++) {
    XMp[(size_t)(r0 + n) * 64 + j] = packxm(axt[n], amt[n] + abj);
    HR[(size_t)(r0 + n) * 64 + j] = make_float2(axh[n] + pbj, fmaxf(ars[n] + rbj, 0.f));
  }
}

// ---------------- lean edge kernel: packed-bf16 XM gathers, window-16 ----------------

__global__ void __launch_bounds__(256, 4) k_edge_lean(
    const int* __restrict__ row_ptr, const int* __restrict__ stb,
    const unsigned int* __restrict__ XMp, const float2* __restrict__ HR,
    const float* __restrict__ wbuf, int l, float* __restrict__ emb) {
  __shared__ float sab[80];
  int tid = threadIdx.x;
  int lane = tid & 63;
  int w = tid >> 6;
  int hh = lane >> 3;
  if (tid < 80) {
    float a = wbuf[W_ABIN + l * 80 + tid];
    sab[tid] = (a > 0.f) ? a : 0.2f * a;
  }
  __syncthreads();
  float av = wbuf[W_AVEC + l * 64 + lane];

  int r = blockIdx.x * 4 + w;
  float2 hr = HR[(size_t)r * 64 + lane];
  int beg = (r == 0) ? 0 : row_ptr[r - 1];
  int end = row_ptr[r];
  beg = __builtin_amdgcn_readfirstlane(beg);
  end = __builtin_amdgcn_readfirstlane(end);

  float xh = hr.x;
  float num = 0.f, den = 0.f;
  for (int j = beg; j < end; j += 16) {
    int pk[16];
    unsigned int xp[16];
#pragma unroll
    for (int k = 0; k < 16; k++) pk[k] = stb[j + k];  // scalar loads
#pragma unroll
    for (int k = 0; k < 16; k++)
      xp[k] = XMp[(size_t)(pk[k] & 0xFFFF) * 64 + lane];  // 16 gathers in flight
#pragma unroll
    for (int k = 0; k < 16; k++) {
      float xt = __uint_as_float(xp[k] << 16);
      float mt = __uint_as_float(xp[k] & 0xFFFF0000u);
      float z = xh + xt;
      z = (z > 0.f) ? z : 0.2f * z;
      float v = z * av;
      v += __shfl_xor(v, 1);
      v += __shfl_xor(v, 2);
      v += __shfl_xor(v, 4);
      float e = __expf(v + sab[(pk[k] >> 16) * 8 + hh]);
      e = (j + k < end) ? e : 0.f;
      den += e;
      num = fmaf(mt, e, num);
    }
  }
  emb[(size_t)r * 64 + lane] = fmaxf(num / (den + 1e-16f), 0.f) + hr.y;
}

// ---------------- XM1 fallback kernels (f32 XM, in-kernel preamble) ----------------

__global__ void k_emb0(const void* __restrict__ A, const int* __restrict__ flag,
                       const float* __restrict__ wbuf, float* __restrict__ emb) {
  int j = threadIdx.x & 63;
  int g = threadIdx.x >> 6;
  int r0 = blockIdx.x * 16 + g * 4;
  int f32 = flag[1];
  __shared__ float sA[16][64];
  for (int k = threadIdx.x; k < 1024; k += 256) {
    int rr = k >> 6, cc = k & 63;
    size_t idx = (size_t)(blockIdx.x * 16 + rr) * 64 + cc;
    sA[rr][cc] = f32 ? ((const float*)A)[idx] : b2f(((const bf16*)A)[idx]);
  }
  __syncthreads();
  const float* W = wbuf + W_P1W;
  float a[4] = {0.f, 0.f, 0.f, 0.f};
  int base = g * 4;
  for (int i = 0; i < 64; i++) {
    float w = W[i * 64 + j];
#pragma unroll
    for (int n = 0; n < 4; n++) a[n] = fmaf(sA[base + n][i], w, a[n]);
  }
  float bj = wbuf[W_P1B + j];
#pragma unroll
  for (int n = 0; n < 4; n++)
    emb[(size_t)(r0 + n) * 64 + j] = fmaxf(a[n] + bj, 0.f);
}

__global__ void k_xm(const float* __restrict__ emb, const float* __restrict__ wbuf, int l,
                     float2* __restrict__ XM) {
  int j = threadIdx.x & 63;
  int g = threadIdx.x >> 6;
  int r0 = blockIdx.x * 16 + g * 4;
  __shared__ float sE[16][64];
  for (int k = threadIdx.x; k < 1024; k += 256) {
    int rr = k >> 6, cc = k & 63;
    sE[rr][cc] = emb[(size_t)(blockIdx.x * 16 + rr) * 64 + cc];
  }
  __syncthreads();
  const float* pwb = wbuf + W_APW + l * 8192 + 4096;
  const float* aw = wbuf + W_AW + l * 4096;
  float axt[4] = {0.f, 0.f, 0.f, 0.f};
  float amt[4] = {0.f, 0.f, 0.f, 0.f};
  int base = g * 4;
  for (int i = 0; i < 64; i++) {
    float wt = pwb[i * 64 + j];
    float wm = aw[i * 64 + j];
#pragma unroll
    for (int n = 0; n < 4; n++) {
      float e = sE[base + n][i];
      axt[n] = fmaf(e, wt, axt[n]);
      amt[n] = fmaf(e, wm, amt[n]);
    }
  }
  float abj = wbuf[W_AB + l * 64 + j];
#pragma unroll
  for (int n = 0; n < 4; n++)
    XM[(size_t)(r0 + n) * 64 + j] = make_float2(axt[n], amt[n] + abj);
}

__global__ void __launch_bounds__(256, 4) k_edge_f(
    const int* __restrict__ row_ptr, const int* __restrict__ stb, const float2* __restrict__ XM,
    const float* __restrict__ wbuf, int l, float* __restrict__ emb) {
  __shared__ float sab[80];
  int tid = threadIdx.x;
  int lane = tid & 63;
  int w = tid >> 6;
  int hh = lane >> 3;
  if (tid < 80) {
    float a = wbuf[W_ABIN + l * 80 + tid];
    sab[tid] = (a > 0.f) ? a : 0.2f * a;
  }
  __syncthreads();

  const float* pwt = wbuf + W_APW + l * 8192;
  const float* rwp = wbuf + W_RW + l * 4096;
  float av = wbuf[W_AVEC + l * 64 + lane];
  float xh0 = wbuf[W_APB + l * 64 + lane];
  float res0 = wbuf[W_RB + l * 64 + lane];

  int r0 = blockIdx.x * 16 + w * 4;
  for (int rr = 0; rr < 4; rr++) {
    int r = r0 + rr;
    float ev = emb[(size_t)r * 64 + lane];
    float xh = xh0, res = res0;
#pragma unroll 16
    for (int i = 0; i < 64; i++) {
      float e = __shfl(ev, i);
      xh = fmaf(e, pwt[i * 64 + lane], xh);
      res = fmaf(e, rwp[i * 64 + lane], res);
    }
    res = fmaxf(res, 0.f);

    int beg = (r == 0) ? 0 : row_ptr[r - 1];
    int end = row_ptr[r];
    beg = __builtin_amdgcn_readfirstlane(beg);
    end = __builtin_amdgcn_readfirstlane(end);

    float num = 0.f, den = 0.f;
    for (int j = beg; j < end; j += 16) {
      int pk[16];
      float2 xmv[16];
#pragma unroll
      for (int k = 0; k < 16; k++) pk[k] = stb[j + k];
#pragma unroll
      for (int k = 0; k < 16; k++) xmv[k] = XM[(size_t)(pk[k] & 0xFFFF) * 64 + lane];
#pragma unroll
      for (int k = 0; k < 16; k++) {
        float z = xh + xmv[k].x;
        z = (z > 0.f) ? z : 0.2f * z;
        float v = z * av;
        v += __shfl_xor(v, 1);
        v += __shfl_xor(v, 2);
        v += __shfl_xor(v, 4);
        float e = __expf(v + sab[(pk[k] >> 16) * 8 + hh]);
        e = (j + k < end) ? e : 0.f;
        den += e;
        num = fmaf(xmv[k].y, e, num);
      }
    }
    emb[(size_t)r * 64 + lane] = fmaxf(num / (den + 1e-16f), 0.f) + res;
  }
}

// ---------------- Plan D fallback (tiny ws): per-edge recompute ----------------

static __device__ __forceinline__ float dotcol(const float* __restrict__ Wm, float val, int lane) {
  float acc = 0.f;
  for (int i = 0; i < 64; i++) acc = fmaf(__shfl(val, i), Wm[i * 64 + lane], acc);
  return acc;
}

template <typename TIN, typename TOUT>
__global__ void k_edge_d(const int* __restrict__ row_ptr, const int* __restrict__ stb,
                         const float* __restrict__ wbuf, int l, const TIN* __restrict__ emb_in,
                         TOUT* __restrict__ emb_out) {
  __shared__ float sab[80];
  int tid = threadIdx.x;
  int lane = tid & 63;
  int w = tid >> 6;
  int r = blockIdx.x * 4 + w;
  int hh = lane >> 3;
  if (tid < 80) {
    float a = wbuf[W_ABIN + l * 80 + tid];
    sab[tid] = (a > 0.f) ? a : 0.2f * a;
  }
  __syncthreads();
  const float* pwt = wbuf + W_APW + l * 8192;
  const float* pwb = pwt + 4096;
  const float* aw = wbuf + W_AW + l * 4096;
  const float* rw = wbuf + W_RW + l * 4096;

  float ev = ldv(emb_in, (size_t)r * 64 + lane);
  float xh = wbuf[W_APB + l * 64 + lane];
  float res = wbuf[W_RB + l * 64 + lane];
  for (int i = 0; i < 64; i++) {
    float e = __shfl(ev, i);
    xh = fmaf(e, pwt[i * 64 + lane], xh);
    res = fmaf(e, rw[i * 64 + lane], res);
  }
  res = fmaxf(res, 0.f);
  float av = wbuf[W_AVEC + l * 64 + lane];
  float abl = wbuf[W_AB + l * 64 + lane];

  int beg = (r == 0) ? 0 : row_ptr[r - 1];
  int end = row_ptr[r];
  float num = 0.f, den = 0.f;
  for (int j = beg; j < end; j++) {
    int p = stb[j];
    int t = p & 0xFFFF;
    float tv = ldv(emb_in, (size_t)t * 64 + lane);
    float z = xh + dotcol(pwb, tv, lane);
    z = (z > 0.f) ? z : 0.2f * z;
    float v = z * av;
    v += __shfl_xor(v, 1);
    v += __shfl_xor(v, 2);
    v += __shfl_xor(v, 4);
    float e = __expf(v + sab[(p >> 16) * 8 + hh]);
    den += e;
    float mt = dotcol(aw, tv, lane) + abl;
    num = fmaf(mt, e, num);
  }
  stv(emb_out, (size_t)r * 64 + lane, fmaxf(num / (den + 1e-16f), 0.f) + res);
}

// ---------------- launch ----------------

extern "C" void kernel_launch(void* const* d_in, const int* in_sizes, int n_in,
                              void* d_out, int out_size, void* d_ws, size_t ws_size,
                              hipStream_t stream) {
  const unsigned int* trip_w = (const unsigned int*)d_in[0];
  const void* rel_emb = d_in[1];
  float* emb = (float*)d_out;

  char* ws = (char*)d_ws;
  int* flag = (int*)(ws + O_FLAG);
  float* wbuf = (float*)(ws + O_WBUF);
  int* row_ptr = (int*)(ws + O_ROWP);
  int* counts = (int*)(ws + O_CNTS);
  int* tmp = (int*)(ws + O_TMP);
  int* partial = (int*)(ws + O_PART);
  int* stb = (int*)(ws + O_STB);
  char* big = ws + O_BIG;

  k_detect_init<<<160, 256, 0, stream>>>(trip_w, (const unsigned short*)rel_emb, flag, counts,
                                         stb);
  int eb_blocks = (E_NUM + 255) / 256;
  k_hist_wconv<<<WCONV_BLOCKS + eb_blocks, 256, 0, stream>>>(
      trip_w, flag, counts, d_in[2], d_in[3], d_in[4], d_in[5], d_in[6], d_in[7], d_in[8],
      d_in[9], d_in[10], d_in[11], wbuf);
  k_scan_a<<<40, 1024, 0, stream>>>(counts, tmp, partial);
  k_scan_c<<<40, 1024, 0, stream>>>(counts, tmp, partial, row_ptr);
  k_scatter<<<eb_blocks, 256, 0, stream>>>(trip_w, flag, row_ptr, stb);

  if (ws_size >= NEED_LEAN) {
    unsigned int* XMp = (unsigned int*)big;
    float2* HR = (float2*)(big + XMP_BYTES);
    k_emb0xm_p<<<R_NUM / 32, 256, 0, stream>>>(rel_emb, flag, wbuf, emb, XMp, HR);
    k_edge_lean<<<R_NUM / 4, 256, 0, stream>>>(row_ptr, stb, XMp, HR, wbuf, 0, emb);
    k_xmhr_p<<<R_NUM / 32, 256, 0, stream>>>(emb, wbuf, 1, XMp, HR);
    k_edge_lean<<<R_NUM / 4, 256, 0, stream>>>(row_ptr, stb, XMp, HR, wbuf, 1, emb);
  } else if (ws_size >= NEED_XM1) {
    float2* XM = (float2*)big;
    k_emb0<<<R_NUM / 16, 256, 0, stream>>>(rel_emb, flag, wbuf, emb);
    k_xm<<<R_NUM / 16, 256, 0, stream>>>(emb, wbuf, 0, XM);
    k_edge_f<<<R_NUM / 16, 256, 0, stream>>>(row_ptr, stb, XM, wbuf, 0, emb);
    k_xm<<<R_NUM / 16, 256, 0, stream>>>(emb, wbuf, 1, XM);
    k_edge_f<<<R_NUM / 16, 256, 0, stream>>>(row_ptr, stb, XM, wbuf, 1, emb);
  } else {
    k_emb0<<<R_NUM / 16, 256, 0, stream>>>(rel_emb, flag, wbuf, emb);
    bf16* embB = (bf16*)big;
    k_edge_d<float, bf16><<<R_NUM / 4, 256, 0, stream>>>(row_ptr, stb, wbuf, 0, emb, embB);
    k_edge_d<bf16, float><<<R_NUM / 4, 256, 0, stream>>>(row_ptr, stb, wbuf, 1, embB, emb);
  }
}